// Round 11
// baseline (383.108 us; speedup 1.0000x reference)
//
#include <hip/hip_runtime.h>
#include <hip/hip_bf16.h>

#define LEAKY(v) ((v) >= 0.f ? (v) : 0.01f * (v))

typedef __attribute__((ext_vector_type(8))) short short8b;
typedef __attribute__((ext_vector_type(4))) float f32x4;
typedef __attribute__((ext_vector_type(4))) unsigned short us4;

__device__ __forceinline__ unsigned short f2b(float f) {
  unsigned int u = __builtin_bit_cast(unsigned int, f);
  return (unsigned short)((u + 0x7FFFu + ((u >> 16) & 1u)) >> 16);
}
__device__ __forceinline__ float b2f(unsigned short s) {
  return __builtin_bit_cast(float, (unsigned int)s << 16);
}

__device__ __forceinline__ void gload16(const unsigned short* g, unsigned short* l) {
  __builtin_amdgcn_global_load_lds(
      (const __attribute__((address_space(1))) unsigned int*)(g),
      (__attribute__((address_space(3))) unsigned int*)(l), 16, 0, 0);
}

// Stage a 64x64 bf16 tile (rows of 128B) global->LDS, XOR-swizzled source.
__device__ __forceinline__ void stage64(const unsigned short* g, int ldg,
                                        unsigned short* lds, int lane, int w) {
  const int r8 = lane >> 3;
  const int ce = ((lane & 7) ^ r8) << 3;
  const int r0 = w * 8 + r8;
  gload16(g + (long)r0 * ldg + ce, lds + w * 512);
  gload16(g + (long)(r0 + 32) * ldg + ce, lds + 2048 + w * 512);
}

// Swizzled 16B read: row, c4 = 16B-column index 0..7
__device__ __forceinline__ short8b ldsw(const unsigned short* base, int row, int c4) {
  return *(const short8b*)&base[row * 64 + (((c4 ^ (row & 7)) << 3))];
}

// ---------------------------------------------------------------------------
// Fused prologue, GRID-STRIDE (G11: full residency + loops, no block churn):
//  blocks [0,2048)      : prep stage A, 4 iterations (8192 logical tiles)
//  blocks [2048,4096)   : enc convert, 4 iterations (8192 logical tiles)
//  blocks [4096,5120)   : enc1 fp32 -> bf16 transpose (1024 tiles)
//  blocks [5120,5888)   : 12x 512x512 weight transpose+convert (w/ scale)
// ---------------------------------------------------------------------------
struct WPtrs { const float* p[12]; float sc[12]; };

__global__ __launch_bounds__(256) void prologue_misc(
    const float* __restrict__ X1, const float* __restrict__ X2,
    float* __restrict__ S, const float* __restrict__ enc1,
    const float* __restrict__ enc2, unsigned short* __restrict__ ENC,
    unsigned short* __restrict__ E1T, WPtrs wp,
    unsigned short* __restrict__ WT) {
  __shared__ float t[64][65];
  const int b = blockIdx.x;
  const int tid = threadIdx.x;
  if (b < 2048) {
    // prep stage A: 4 logical tiles per block
#pragma unroll
    for (int it = 0; it < 4; ++it) {
      const int lb = b + it * 2048;
      const int tt = lb & 63, y = (lb >> 6) & 15, z = lb >> 10;
      const float* X = (z >> 2) ? X2 : X1;
      const int n = z & 3;
      const long base = (((long)n * 64 + y * 4) * 64 + tt) * 1024 + tid * 4;
      const float4 a = *(const float4*)&X[base];
      const float4 bb = *(const float4*)&X[base + 65536];
      const float4 c = *(const float4*)&X[base + 2 * 65536];
      const float4 d = *(const float4*)&X[base + 3 * 65536];
      float4 o;
      o.x = (a.x + bb.x) + (c.x + d.x);
      o.y = (a.y + bb.y) + (c.y + d.y);
      o.z = (a.z + bb.z) + (c.z + d.z);
      o.w = (a.w + bb.w) + (c.w + d.w);
      *(float4*)&S[(((long)z * 16 + y) * 64 + tt) * 1024 + tid * 4] = o;
    }
  } else if (b < 4096) {
    // enc convert: 4 logical tiles per block
#pragma unroll
    for (int it = 0; it < 4; ++it) {
      const int cb = (b - 2048) + it * 2048;
      const int z = cb >> 12;
      const float* in = z ? enc2 : enc1;
      unsigned short* o = ENC + (long)z * (4L << 20);
      const long i = (long)(cb & 4095) * 256 + tid;
      const float4 v = ((const float4*)in)[i];
      us4 q;
      q[0] = f2b(v.x); q[1] = f2b(v.y); q[2] = f2b(v.z); q[3] = f2b(v.w);
      ((us4*)o)[i] = q;
    }
  } else if (b < 5120) {
    // enc1 transpose -> E1T (out 1024 x 4096)
    const int b3 = b - 4096;
    const int c0 = (b3 & 15) * 64, r0 = (b3 >> 4) * 64;
#pragma unroll
    for (int it = 0; it < 4; ++it) {
      int idx = tid + it * 256;
      int r = idx >> 4, c4 = (idx & 15) * 4;
      float4 v = *(const float4*)&enc1[(long)(r0 + r) * 1024 + c0 + c4];
      t[c4 + 0][r] = v.x; t[c4 + 1][r] = v.y;
      t[c4 + 2][r] = v.z; t[c4 + 3][r] = v.w;
    }
    __syncthreads();
#pragma unroll
    for (int it = 0; it < 4; ++it) {
      int idx = tid + it * 256;
      int c = idx >> 4, r4 = (idx & 15) * 4;
      us4 o;
      o[0] = f2b(t[c][r4 + 0]); o[1] = f2b(t[c][r4 + 1]);
      o[2] = f2b(t[c][r4 + 2]); o[3] = f2b(t[c][r4 + 3]);
      *(us4*)&E1T[(long)(c0 + c) * 4096 + r0 + r4] = o;
    }
  } else {
    // weight transpose+convert
    const int b4 = b - 5120;
    const int x = b4 & 7, y = (b4 >> 3) & 7, z = b4 >> 6;
    const float* in = wp.p[z];
    const float s = wp.sc[z];
    unsigned short* ob = WT + (long)z * 262144;
    const int c0 = x * 64, r0 = y * 64;
#pragma unroll
    for (int it = 0; it < 4; ++it) {
      int idx = tid + it * 256;
      int r = idx >> 4, c4 = (idx & 15) * 4;
      float4 v = *(const float4*)&in[(long)(r0 + r) * 512 + c0 + c4];
      t[c4 + 0][r] = v.x; t[c4 + 1][r] = v.y;
      t[c4 + 2][r] = v.z; t[c4 + 3][r] = v.w;
    }
    __syncthreads();
#pragma unroll
    for (int it = 0; it < 4; ++it) {
      int idx = tid + it * 256;
      int c = idx >> 4, r4 = (idx & 15) * 4;
      us4 o;
      o[0] = f2b(t[c][r4 + 0] * s); o[1] = f2b(t[c][r4 + 1] * s);
      o[2] = f2b(t[c][r4 + 2] * s); o[3] = f2b(t[c][r4 + 3] * s);
      *(us4*)&ob[(long)(c0 + c) * 512 + r0 + r4] = o;
    }
  }
}

// ---------------------------------------------------------------------------
// prep stage B: combine 4 sub-window partials, write pooled^T bf16.
// ---------------------------------------------------------------------------
__global__ __launch_bounds__(256) void prep_finish(const float* __restrict__ S,
                                                   unsigned short* __restrict__ Pt) {
  const int t = blockIdx.x;   // 0..63
  const int cbi = blockIdx.y; // 0..3
  const int z = blockIdx.z;   // inp*4+n
  const int n = z & 3, inp = z >> 2;
  const int tid = threadIdx.x;
  __shared__ unsigned short sacc[64][20];
  const long sb = (((long)z * 16 + cbi * 4) * 64 + t) * 1024 + tid * 4;
  const float4 a = *(const float4*)&S[sb];
  const float4 b = *(const float4*)&S[sb + 65536];
  const float4 c = *(const float4*)&S[sb + 2 * 65536];
  const float4 d = *(const float4*)&S[sb + 3 * 65536];
  float acc[4];
  acc[0] = (a.x + b.x) + (c.x + d.x);
  acc[1] = (a.y + b.y) + (c.y + d.y);
  acc[2] = (a.z + b.z) + (c.z + d.z);
  acc[3] = (a.w + b.w) + (c.w + d.w);
  const int q = tid & 15, vb = tid >> 4;
#pragma unroll
  for (int j = 0; j < 4; ++j)
    sacc[q * 4 + j][vb] = f2b(acc[j] * (1.f / 16.f));
  __syncthreads();
  const int vvv = tid >> 2, iq = tid & 3;
  const us4 o = *(const us4*)&sacc[vvv][iq * 4];
  *(us4*)&Pt[(long)inp * (1L << 20) + (long)n * 262144 +
             (long)(vvv * 4 + cbi) * 1024 + t * 16 + iq * 4] = o;
}

// sum 4 bf16 split-K partials, convert to bf16. Grid-stride (1024 x 4).
__global__ __launch_bounds__(256) void addcvt4(const unsigned short* __restrict__ P,
                                               unsigned short* __restrict__ out) {
#pragma unroll
  for (int it = 0; it < 4; ++it) {
    const long i = ((long)(blockIdx.x + it * 1024) * 256 + threadIdx.x) * 4;
    const us4 a = *(const us4*)&P[i];
    const us4 b = *(const us4*)&P[i + 4194304];
    const us4 c = *(const us4*)&P[i + 2 * 4194304];
    const us4 d = *(const us4*)&P[i + 3 * 4194304];
    us4 o;
#pragma unroll
    for (int j = 0; j < 4; ++j)
      o[j] = f2b((b2f(a[j]) + b2f(b[j])) + (b2f(c[j]) + b2f(d[j])));
    *(us4*)&out[i] = o;
  }
}

// ---------------------------------------------------------------------------
// bf16 MFMA GEMM, 128x128 tile, BK=64, 4 waves; XOR-swizzled LDS.
// CMODE: 0 fp32; 1 bf16; 2 V^T layout; 3 C^T; 4 per-desc (mode==2 -> V^T).
// KSPLIT: s = bz%KSPLIT shifts A/B cols by s*K and C by s*sC2.
// ---------------------------------------------------------------------------
struct GDesc { const unsigned short* A; const unsigned short* B; long coff;
               const float* bias; int mode; float bscale; };
struct GDescs { GDesc d[16]; };

template <int ACT, int CMODE, int KSPLIT>
__global__ __launch_bounds__(256) void gemm_z(
    GDescs ga, void* __restrict__ Cv, int K, int lda, int ldb, int ldc,
    long sC2, float alpha) {
  const int bz = blockIdx.z;
  const int s = (KSPLIT > 1) ? (bz % KSPLIT) : 0;
  const int zb = (KSPLIT > 1) ? (bz / KSPLIT) : bz;
  const GDesc g = ga.d[zb];
  const unsigned short* Ab = g.A + (long)s * K;
  const unsigned short* Bb = g.B + (long)s * K;
  const int m0 = blockIdx.y * 128, n0 = blockIdx.x * 128;
  const int tid = threadIdx.x;
  const int lane = tid & 63, w = tid >> 6;
  const int wr = (w >> 1) * 64, wc = (w & 1) * 64;
  __shared__ unsigned short As[128 * 64];
  __shared__ unsigned short Bs[128 * 64];
  f32x4 acc[4][4];
#pragma unroll
  for (int i = 0; i < 4; ++i)
#pragma unroll
    for (int j = 0; j < 4; ++j) acc[i][j] = (f32x4){0.f, 0.f, 0.f, 0.f};
  const int srow = tid >> 3;
  const int scol = (((tid & 7) ^ ((tid >> 3) & 7)) << 3);
  const int rl = lane & 15, lg = lane >> 4, rx = rl & 7;
  for (int k0 = 0; k0 < K; k0 += 64) {
    __syncthreads();
#pragma unroll
    for (int it = 0; it < 4; ++it) {
      gload16(Ab + (long)(m0 + it * 32 + srow) * lda + k0 + scol,
              As + w * 512 + it * 2048);
      gload16(Bb + (long)(n0 + it * 32 + srow) * ldb + k0 + scol,
              Bs + w * 512 + it * 2048);
    }
    __syncthreads();
#pragma unroll
    for (int kk = 0; kk < 2; ++kk) {
      short8b af[4], bfr[4];
#pragma unroll
      for (int m = 0; m < 4; ++m)
        af[m] = *(const short8b*)&As[(wr + m * 16 + rl) * 64 +
                                     ((((kk * 4 + lg) ^ rx)) << 3)];
#pragma unroll
      for (int nn = 0; nn < 4; ++nn)
        bfr[nn] = *(const short8b*)&Bs[(wc + nn * 16 + rl) * 64 +
                                       ((((kk * 4 + lg) ^ rx)) << 3)];
#pragma unroll
      for (int m = 0; m < 4; ++m)
#pragma unroll
        for (int nn = 0; nn < 4; ++nn)
          acc[m][nn] = __builtin_amdgcn_mfma_f32_16x16x32_bf16(
              af[m], bfr[nn], acc[m][nn], 0, 0, 0);
    }
  }
  const int rrow = lg * 4;
  float bv[4];
#pragma unroll
  for (int nn = 0; nn < 4; ++nn)
    bv[nn] = g.bias ? g.bias[n0 + wc + nn * 16 + rl] * g.bscale : 0.f;
  const bool vt_layout = (CMODE == 2) || (CMODE == 4 && g.mode == 2);
  if (CMODE == 2 || CMODE == 4) {
    if (vt_layout) {
#pragma unroll
      for (int m = 0; m < 4; ++m)
#pragma unroll
        for (int nn = 0; nn < 4; ++nn) {
          const int row = m0 + wr + m * 16 + rrow;
          const int col = n0 + wc + nn * 16 + rl;
          us4 o;
#pragma unroll
          for (int r = 0; r < 4; ++r) {
            float v = alpha * acc[m][nn][r] + bv[nn];
            if (ACT == 1) v = LEAKY(v);
            o[r] = f2b(v);
          }
          const long off = g.coff + (long)(row >> 10) * 524288 +
                           (long)col * 1024 + (row & 1023);
          *(us4*)&((unsigned short*)Cv)[off] = o;
        }
    } else {
#pragma unroll
      for (int m = 0; m < 4; ++m)
#pragma unroll
        for (int nn = 0; nn < 4; ++nn)
#pragma unroll
          for (int r = 0; r < 4; ++r) {
            float v = alpha * acc[m][nn][r] + bv[nn];
            if (ACT == 1) v = LEAKY(v);
            const long off = g.coff +
                             (long)(m0 + wr + m * 16 + rrow + r) * ldc + n0 +
                             wc + nn * 16 + rl;
            ((unsigned short*)Cv)[off] = f2b(v);
          }
    }
  } else if (CMODE == 3) {
#pragma unroll
    for (int m = 0; m < 4; ++m)
#pragma unroll
      for (int nn = 0; nn < 4; ++nn) {
        const int row = m0 + wr + m * 16 + rrow;
        const int col = n0 + wc + nn * 16 + rl;
        us4 o;
#pragma unroll
        for (int r = 0; r < 4; ++r) {
          float v = alpha * acc[m][nn][r] + bv[nn];
          if (ACT == 1) v = LEAKY(v);
          o[r] = f2b(v);
        }
        *(us4*)&((unsigned short*)Cv)[g.coff + (long)col * ldc + row] = o;
      }
  } else {
#pragma unroll
    for (int m = 0; m < 4; ++m)
#pragma unroll
      for (int nn = 0; nn < 4; ++nn)
#pragma unroll
        for (int r = 0; r < 4; ++r) {
          float v = alpha * acc[m][nn][r] + bv[nn];
          if (ACT == 1) v = LEAKY(v);
          long off = g.coff + (long)s * sC2 +
                     (long)(m0 + wr + m * 16 + rrow + r) * ldc + n0 + wc +
                     nn * 16 + rl;
          if (CMODE == 1)
            ((unsigned short*)Cv)[off] = f2b(v);
          else
            ((float*)Cv)[off] = v;
        }
  }
}

// ---------------------------------------------------------------------------
// Fused BatchNorm on h^T (512 features x 16384 samples), bf16, in-place.
// ---------------------------------------------------------------------------
__global__ __launch_bounds__(256) void bn_fused(
    unsigned short* __restrict__ X,
    const float* __restrict__ g1, const float* __restrict__ be1,
    const float* __restrict__ g2, const float* __restrict__ be2) {
  const int f = blockIdx.x;
  const int z = blockIdx.z;
  unsigned short* p = X + (long)z * (8L << 20) + (long)f * 16384;
  const int tid = threadIdx.x;
  us4 v[16];
  float s = 0.f, q = 0.f;
#pragma unroll
  for (int k = 0; k < 16; ++k) {
    v[k] = *(const us4*)&p[(k * 256 + tid) * 4];
#pragma unroll
    for (int j = 0; j < 4; ++j) {
      const float x = b2f(v[k][j]);
      s += x; q += x * x;
    }
  }
#pragma unroll
  for (int mask = 1; mask < 64; mask <<= 1) {
    s += __shfl_xor(s, mask, 64);
    q += __shfl_xor(q, mask, 64);
  }
  __shared__ float rs[8];
  const int wv = tid >> 6;
  if ((tid & 63) == 0) { rs[wv] = s; rs[4 + wv] = q; }
  __syncthreads();
  s = rs[0] + rs[1] + rs[2] + rs[3];
  q = rs[4] + rs[5] + rs[6] + rs[7];
  const float mu = s * (1.f / 16384.f);
  const float var = q * (1.f / 16384.f) - mu * mu;
  const float gg = (z ? g2 : g1)[f];
  const float bb0 = (z ? be2 : be1)[f];
  const float rstd = rsqrtf(var + 1e-5f) * gg;
  const float bb = bb0 - mu * rstd;
#pragma unroll
  for (int k = 0; k < 16; ++k) {
    us4 o;
#pragma unroll
    for (int j = 0; j < 4; ++j) {
      const float y = b2f(v[k][j]) * rstd + bb;
      o[j] = f2b(LEAKY(y));
    }
    *(us4*)&p[(k * 256 + tid) * 4] = o;
  }
}

// ---------------------------------------------------------------------------
// bf16 MFMA flash attention, both attentions in one dispatch (z = 8).
// NO-MAX softmax (Q pre-scaled to log2 domain); Q fragments hoisted to regs.
// ---------------------------------------------------------------------------
__global__ __launch_bounds__(256) void attn_mfma(
    const unsigned short* __restrict__ Q, const unsigned short* __restrict__ K,
    const unsigned short* __restrict__ Vt, unsigned short* __restrict__ O) {
  const int qb = blockIdx.x, h = blockIdx.y;
  const int n = blockIdx.z & 3, sel = blockIdx.z >> 2;
  Q += (long)sel * 4194304;
  K += (long)sel * 4194304;
  Vt += (long)sel * 2097152;
  O += (long)sel * 2097152;
  const int tid = threadIdx.x;
  const int lane = tid & 63, w = tid >> 6;
  const int rl = lane & 15, lg = lane >> 4;
  __shared__ unsigned short Qs[4096];
  __shared__ unsigned short Ks[4096];
  __shared__ unsigned short Vs[4096];
  __shared__ unsigned short Ps[4096];
  stage64(Q + ((long)n * 1024 + qb * 64) * 512 + h * 64, 512, Qs, lane, w);
  __syncthreads();
  const int q = w * 16 + rl;
  const short8b qr0 = ldsw(Qs, q, lg);
  const short8b qr1 = ldsw(Qs, q, 4 + lg);
  float l_r = 0.f;
  f32x4 po[4];
#pragma unroll
  for (int i = 0; i < 4; ++i) po[i] = (f32x4){0.f, 0.f, 0.f, 0.f};
  const unsigned short* Kg0 = K + ((long)n * 1024) * 512 + h * 64;
  const unsigned short* Vg0 = Vt + (long)n * 524288 + (long)(h * 64) * 1024;
  for (int kt = 0; kt < 16; ++kt) {
    __syncthreads();
    stage64(Kg0 + (long)(kt * 64) * 512, 512, Ks, lane, w);
    stage64(Vg0 + kt * 64, 1024, Vs, lane, w);
    __syncthreads();
    f32x4 sa[4];
#pragma unroll
    for (int i = 0; i < 4; ++i) sa[i] = (f32x4){0.f, 0.f, 0.f, 0.f};
#pragma unroll
    for (int kk = 0; kk < 2; ++kk) {
      const short8b qf = kk ? qr1 : qr0;
#pragma unroll
      for (int mt = 0; mt < 4; ++mt) {
        const short8b kf = ldsw(Ks, mt * 16 + rl, 4 * kk + lg);
        sa[mt] = __builtin_amdgcn_mfma_f32_16x16x32_bf16(kf, qf, sa[mt], 0, 0, 0);
      }
    }
    float ps = 0.f;
#pragma unroll
    for (int mt = 0; mt < 4; ++mt) {
      us4 o;
#pragma unroll
      for (int r = 0; r < 4; ++r) {
        const float p = exp2f(sa[mt][r]);
        ps += p;
        o[r] = f2b(p);
      }
      const int c16 = (4 * mt + lg) >> 1;
      *(us4*)&Ps[q * 64 + ((c16 ^ (q & 7)) << 3) + ((lg & 1) << 2)] = o;
    }
    ps += __shfl_xor(ps, 16, 64);
    ps += __shfl_xor(ps, 32, 64);
    l_r += ps;
#pragma unroll
    for (int kk = 0; kk < 2; ++kk) {
      const short8b pf = ldsw(Ps, q, 4 * kk + lg);
#pragma unroll
      for (int nt = 0; nt < 4; ++nt) {
        const short8b vf = ldsw(Vs, nt * 16 + rl, 4 * kk + lg);
        po[nt] = __builtin_amdgcn_mfma_f32_16x16x32_bf16(pf, vf, po[nt], 0, 0, 0);
      }
    }
  }
  float invr[4];
#pragma unroll
  for (int r = 0; r < 4; ++r) invr[r] = 1.f / __shfl(l_r, lg * 4 + r, 64);
  const long ob = ((long)n * 1024 + qb * 64 + w * 16) * 512 + h * 64;
#pragma unroll
  for (int nt = 0; nt < 4; ++nt)
#pragma unroll
    for (int r = 0; r < 4; ++r)
      O[ob + (long)(lg * 4 + r) * 512 + nt * 16 + rl] = f2b(po[nt][r] * invr[r]);
}

// ---------------------------------------------------------------------------
// Softmax pass 1: per-row max & 1/sum, plus column sums of softmax(A).
// ---------------------------------------------------------------------------
__global__ __launch_bounds__(256) void softmax_cs(const float* __restrict__ D,
                                                  float* __restrict__ RS,
                                                  float* __restrict__ CS) {
  __shared__ float colacc[2048];
  __shared__ float red[8];
  const int tid = threadIdx.x;
  const int wv = tid >> 6, ln = tid & 63;
#pragma unroll
  for (int k = 0; k < 8; ++k) colacc[tid + k * 256] = 0.f;
  __syncthreads();
  const int r0 = blockIdx.x * 8;
  const int n = r0 >> 11;
  for (int rr = 0; rr < 8; ++rr) {
    const float* p = D + (long)(r0 + rr) * 2048;
    float v[8];
    float mx = -1e30f;
#pragma unroll
    for (int k = 0; k < 8; ++k) {
      v[k] = p[tid + k * 256];
      mx = fmaxf(mx, v[k]);
    }
#pragma unroll
    for (int mask = 1; mask < 64; mask <<= 1) mx = fmaxf(mx, __shfl_xor(mx, mask, 64));
    if (ln == 0) red[wv] = mx;
    __syncthreads();
    mx = fmaxf(fmaxf(red[0], red[1]), fmaxf(red[2], red[3]));
    float sum = 0.f;
#pragma unroll
    for (int k = 0; k < 8; ++k) {
      v[k] = __expf(v[k] - mx);
      sum += v[k];
    }
#pragma unroll
    for (int mask = 1; mask < 64; mask <<= 1) sum += __shfl_xor(sum, mask, 64);
    if (ln == 0) red[4 + wv] = sum;
    __syncthreads();
    sum = red[4] + red[5] + red[6] + red[7];
    const float inv = 1.f / sum;
    if (tid == 0) {
      RS[(r0 + rr) * 2] = mx;
      RS[(r0 + rr) * 2 + 1] = inv;
    }
#pragma unroll
    for (int k = 0; k < 8; ++k) colacc[tid + k * 256] += v[k] * inv;
    __syncthreads();
  }
#pragma unroll
  for (int k = 0; k < 8; ++k)
    atomicAdd(&CS[n * 2048 + tid + k * 256], colacc[tid + k * 256]);
}

// Pass 2: recompute softmax, apply column normalize. Grid-stride (2048 x 8).
__global__ __launch_bounds__(256) void final_scale(float* __restrict__ D,
                                                   const float* __restrict__ RS,
                                                   const float* __restrict__ CS) {
#pragma unroll
  for (int it = 0; it < 8; ++it) {
    const long i = ((long)(blockIdx.x + it * 2048) * 256 + threadIdx.x) * 4;
    const long row = i >> 11;
    const int n = (int)(row >> 11);
    const int j = (int)(i & 2047);
    const float mx = RS[row * 2];
    const float inv = RS[row * 2 + 1];
    float4 v = *(float4*)&D[i];
    const float* c = &CS[n * 2048 + j];
    v.x = __expf(v.x - mx) * inv * (c[0] > 0.f ? 1.f / c[0] : 0.f);
    v.y = __expf(v.y - mx) * inv * (c[1] > 0.f ? 1.f / c[1] : 0.f);
    v.z = __expf(v.z - mx) * inv * (c[2] > 0.f ? 1.f / c[2] : 0.f);
    v.w = __expf(v.w - mx) * inv * (c[3] > 0.f ? 1.f / c[3] : 0.f);
    *(float4*)&D[i] = v;
  }
}

// ---------------------------------------------------------------------------
extern "C" void kernel_launch(void* const* d_in, const int* in_sizes, int n_in,
                              void* d_out, int out_size, void* d_ws,
                              size_t ws_size, hipStream_t stream) {
  const float* x1 = (const float*)d_in[0];
  const float* x2 = (const float*)d_in[1];
  const float* enc1 = (const float*)d_in[2];
  const float* enc2 = (const float*)d_in[3];
  const float* mlp_b1 = (const float*)d_in[5];
  const float* mlp_b2 = (const float*)d_in[7];
  const float* mlp_g = (const float*)d_in[8];
  const float* mlp_be = (const float*)d_in[9];
  const float* nlp_b1 = (const float*)d_in[11];
  const float* nlp_b2 = (const float*)d_in[13];
  const float* nlp_g = (const float*)d_in[14];
  const float* nlp_be = (const float*)d_in[15];
  float* out = (float*)d_out;

  unsigned short* W = (unsigned short*)d_ws;
  const long M1 = 1L << 20;
  const long S = 262144;
  const float K2 = 0.18033688f;  // 0.125 * log2(e)
  // Rolling layout (us units), lifetimes disjoint-in-time (R6 audit + R9):
  unsigned short* Pt = W;
  unsigned short* ENC = W + 4 * M1;
  unsigned short* E1T = W + 12 * M1;
  unsigned short* WT = W + 16 * M1;
  unsigned short* NE = W + 20 * M1;
  unsigned short* H1T = W + 20 * M1;
  unsigned short* MID = W + 36 * M1;
  float* Sprep = (float*)(W + 36 * M1);
  unsigned short* PB = W + 36 * M1;   // edge bf16 split-K partials (16M us)
  unsigned short* E1 = W + 4 * M1;
  unsigned short* E2 = W + 6 * M1;
  unsigned short* QKV = W + 36 * M1;
  unsigned short* VT = W + 44 * M1;
  unsigned short* AO = W + 48 * M1;
  unsigned short* A1P = W + 8 * M1;
  unsigned short* A2P = W + 10 * M1;
  float* ST = (float*)(W + 56 * M1);
  float* CS = ST + 2048;
  float* RS = CS + 8192;

  const dim3 T(256);
  const long sP = 262144;
  const long sNE = 2097152;
  const long sE = 524288;
  const long sD = 4194304;

  // --- CS memset early (region dead until softmax) ---
  hipMemsetAsync(CS, 0, 8192 * sizeof(float), stream);

  // --- fused prologue (grid-stride) ---
  WPtrs wp;
  wp.p[0] = (const float*)d_in[4];   wp.sc[0] = 1.f;   // mlp_w1
  wp.p[1] = (const float*)d_in[6];   wp.sc[1] = 1.f;   // mlp_w2
  wp.p[2] = (const float*)d_in[10];  wp.sc[2] = 1.f;   // nlp_w1
  wp.p[3] = (const float*)d_in[12];  wp.sc[3] = 1.f;   // nlp_w2
  wp.p[4] = (const float*)d_in[16];  wp.sc[4] = K2;    // a1_wq (log2-scaled)
  wp.p[5] = (const float*)d_in[18];  wp.sc[5] = 1.f;   // a1_wk
  wp.p[6] = (const float*)d_in[24];  wp.sc[6] = K2;    // a2_wq (log2-scaled)
  wp.p[7] = (const float*)d_in[26];  wp.sc[7] = 1.f;   // a2_wk
  wp.p[8] = (const float*)d_in[20];  wp.sc[8] = 1.f;   // a1_wv
  wp.p[9] = (const float*)d_in[28];  wp.sc[9] = 1.f;   // a2_wv
  wp.p[10] = (const float*)d_in[22]; wp.sc[10] = 1.f;  // a1_fc
  wp.p[11] = (const float*)d_in[30]; wp.sc[11] = 1.f;  // a2_fc
  prologue_misc<<<5888, T, 0, stream>>>(x1, x2, Sprep, enc1, enc2, ENC, E1T,
                                        wp, WT);
  prep_finish<<<dim3(64, 4, 8), T, 0, stream>>>(Sprep, Pt);

  // --- node_enc for BOTH branches: z=16 (inp x pr x n) -> NE ---
  {
    GDescs g{};
    for (int inp = 0; inp < 2; ++inp)
      for (int pr = 0; pr < 2; ++pr)
        for (int nn = 0; nn < 4; ++nn)
          g.d[inp * 8 + pr * 4 + nn] = {
              ENC + (long)pr * (4 * M1), Pt + (long)inp * M1 + nn * sP,
              (long)inp * (8 * M1) + (long)nn * sNE + pr * 256, nullptr, 0, 1.f};
    gemm_z<0, 1, 1><<<dim3(2, 32, 16), T, 0, stream>>>(g, NE, 1024, 1024,
                                                       1024, 512, 0, 1.f);
  }
  // --- lin1 both branches (z=2) -> MID ---
  {
    GDescs g{};
    g.d[0] = {NE, WT + 0 * S, 0, mlp_b1, 0, 1.f};
    g.d[1] = {NE + 8 * M1, WT + 2 * S, 8 * M1, nlp_b1, 0, 1.f};
    gemm_z<1, 1, 1><<<dim3(4, 128, 2), T, 0, stream>>>(g, MID, 512, 512, 512,
                                                       512, 0, 1.f);
  }
  // --- lin2^T both branches (z=2) -> H1T/H2T (over NE, dead) ---
  {
    GDescs g{};
    g.d[0] = {MID, WT + 1 * S, 0, mlp_b2, 0, 1.f};
    g.d[1] = {MID + 8 * M1, WT + 3 * S, 8 * M1, nlp_b2, 0, 1.f};
    gemm_z<0, 3, 1><<<dim3(4, 128, 2), T, 0, stream>>>(g, H1T, 512, 512, 512,
                                                       16384, 0, 1.f);
  }
  bn_fused<<<dim3(512, 1, 2), T, 0, stream>>>(H1T, mlp_g, mlp_be, nlp_g, nlp_be);

  // --- edge decode: z = 8 descs x split-K 4, bf16 partials in MID region ---
  {
    GDescs g{};
    for (int d = 0; d < 8; ++d)
      g.d[d] = {E1T, H1T + (long)(d >> 2) * (8 * M1) + (d & 3) * 4096,
                (long)d * 524288, nullptr, 0, 1.f};
    gemm_z<0, 1, 4><<<dim3(4, 8, 32), T, 0, stream>>>(g, PB, 1024, 4096,
                                                      16384, 512, 4194304,
                                                      1.f / 1024.f);
  }
  addcvt4<<<1024, T, 0, stream>>>(PB, E1);

  // --- projections: Q1,K1,Q2,K2,V1,V2 in ONE dispatch (z=6, per-desc mode) ---
  {
    GDescs g{};
    g.d[0] = {E2, WT + 4 * S, 0, (const float*)d_in[17], 1, K2};
    g.d[1] = {E1, WT + 5 * S, 2 * M1, (const float*)d_in[19], 1, 1.f};
    g.d[2] = {E1, WT + 6 * S, 4 * M1, (const float*)d_in[25], 1, K2};
    g.d[3] = {E2, WT + 7 * S, 6 * M1, (const float*)d_in[27], 1, 1.f};
    g.d[4] = {E1, WT + 8 * S, 8 * M1, (const float*)d_in[21], 2, 1.f};
    g.d[5] = {E2, WT + 9 * S, 10 * M1, (const float*)d_in[29], 2, 1.f};
    gemm_z<0, 4, 1><<<dim3(4, 32, 6), T, 0, stream>>>(g, QKV, 512, 512, 512,
                                                      512, 0, 1.f);
  }

  // --- both attentions ---
  attn_mfma<<<dim3(16, 8, 8), T, 0, stream>>>(QKV, QKV + 2 * M1, VT, AO);

  // --- fc for both attentions -> A1P/A2P ---
  {
    GDescs g{};
    g.d[0] = {AO, WT + 10 * S, 0, (const float*)d_in[23], 0, 1.f};
    g.d[1] = {AO + 2 * M1, WT + 11 * S, 2 * M1, (const float*)d_in[31], 0, 1.f};
    gemm_z<0, 1, 1><<<dim3(4, 32, 2), T, 0, stream>>>(g, A1P, 512, 512, 512,
                                                      512, 0, 1.f);
  }

  // --- logits: all 4 quadrants x 4 n in one dispatch (z=16) ---
  {
    GDescs g{};
    for (int q = 0; q < 4; ++q)
      for (int n = 0; n < 4; ++n) {
        const unsigned short* A = (q < 2 ? A1P : A2P) + n * sE;
        const unsigned short* B = ((q == 0 || q == 2) ? A2P : A1P) + n * sE;
        const long coff =
            (long)n * sD + (q & 1) * 1024 + (long)(q >> 1) * 2097152;
        g.d[q * 4 + n] = {A, B, coff, nullptr, 0, 1.f};
      }
    gemm_z<0, 0, 1><<<dim3(8, 8, 16), T, 0, stream>>>(g, out, 512, 512, 512,
                                                      2048, 0, 1.f);
  }

  // --- softmax + column normalization (2 passes, no middle write) ---
  softmax_cs<<<1024, T, 0, stream>>>(out, RS, CS);
  final_scale<<<2048, T, 0, stream>>>(out, RS, CS);
}

// Round 12
// 382.609 us; speedup vs baseline: 1.0013x; 1.0013x over previous
//
#include <hip/hip_runtime.h>
#include <hip/hip_bf16.h>

#define LEAKY(v) ((v) >= 0.f ? (v) : 0.01f * (v))

typedef __attribute__((ext_vector_type(8))) short short8b;
typedef __attribute__((ext_vector_type(4))) float f32x4;
typedef __attribute__((ext_vector_type(4))) unsigned short us4;

__device__ __forceinline__ unsigned short f2b(float f) {
  unsigned int u = __builtin_bit_cast(unsigned int, f);
  return (unsigned short)((u + 0x7FFFu + ((u >> 16) & 1u)) >> 16);
}
__device__ __forceinline__ float b2f(unsigned short s) {
  return __builtin_bit_cast(float, (unsigned int)s << 16);
}

__device__ __forceinline__ void gload16(const unsigned short* g, unsigned short* l) {
  __builtin_amdgcn_global_load_lds(
      (const __attribute__((address_space(1))) unsigned int*)(g),
      (__attribute__((address_space(3))) unsigned int*)(l), 16, 0, 0);
}

// Stage a 64x64 bf16 tile (rows of 128B) global->LDS, XOR-swizzled source.
__device__ __forceinline__ void stage64(const unsigned short* g, int ldg,
                                        unsigned short* lds, int lane, int w) {
  const int r8 = lane >> 3;
  const int ce = ((lane & 7) ^ r8) << 3;
  const int r0 = w * 8 + r8;
  gload16(g + (long)r0 * ldg + ce, lds + w * 512);
  gload16(g + (long)(r0 + 32) * ldg + ce, lds + 2048 + w * 512);
}

// Swizzled 16B read: row, c4 = 16B-column index 0..7
__device__ __forceinline__ short8b ldsw(const unsigned short* base, int row, int c4) {
  return *(const short8b*)&base[row * 64 + (((c4 ^ (row & 7)) << 3))];
}

// ---------------------------------------------------------------------------
// Fused prologue, GRID-STRIDE (G11: full residency + loops, no block churn):
//  blocks [0,2048)      : prep stage A, 4 iterations (8192 logical tiles)
//  blocks [2048,4096)   : enc convert, 4 iterations (8192 logical tiles)
//  blocks [4096,5120)   : enc1 fp32 -> bf16 transpose (1024 tiles)
//  blocks [5120,5888)   : 12x 512x512 weight transpose+convert (w/ scale)
// ---------------------------------------------------------------------------
struct WPtrs { const float* p[12]; float sc[12]; };

__global__ __launch_bounds__(256) void prologue_misc(
    const float* __restrict__ X1, const float* __restrict__ X2,
    float* __restrict__ S, const float* __restrict__ enc1,
    const float* __restrict__ enc2, unsigned short* __restrict__ ENC,
    unsigned short* __restrict__ E1T, WPtrs wp,
    unsigned short* __restrict__ WT) {
  __shared__ float t[64][65];
  const int b = blockIdx.x;
  const int tid = threadIdx.x;
  if (b < 2048) {
    // prep stage A: 4 logical tiles per block
#pragma unroll
    for (int it = 0; it < 4; ++it) {
      const int lb = b + it * 2048;
      const int tt = lb & 63, y = (lb >> 6) & 15, z = lb >> 10;
      const float* X = (z >> 2) ? X2 : X1;
      const int n = z & 3;
      const long base = (((long)n * 64 + y * 4) * 64 + tt) * 1024 + tid * 4;
      const float4 a = *(const float4*)&X[base];
      const float4 bb = *(const float4*)&X[base + 65536];
      const float4 c = *(const float4*)&X[base + 2 * 65536];
      const float4 d = *(const float4*)&X[base + 3 * 65536];
      float4 o;
      o.x = (a.x + bb.x) + (c.x + d.x);
      o.y = (a.y + bb.y) + (c.y + d.y);
      o.z = (a.z + bb.z) + (c.z + d.z);
      o.w = (a.w + bb.w) + (c.w + d.w);
      *(float4*)&S[(((long)z * 16 + y) * 64 + tt) * 1024 + tid * 4] = o;
    }
  } else if (b < 4096) {
    // enc convert: 4 logical tiles per block
#pragma unroll
    for (int it = 0; it < 4; ++it) {
      const int cb = (b - 2048) + it * 2048;
      const int z = cb >> 12;
      const float* in = z ? enc2 : enc1;
      unsigned short* o = ENC + (long)z * (4L << 20);
      const long i = (long)(cb & 4095) * 256 + tid;
      const float4 v = ((const float4*)in)[i];
      us4 q;
      q[0] = f2b(v.x); q[1] = f2b(v.y); q[2] = f2b(v.z); q[3] = f2b(v.w);
      ((us4*)o)[i] = q;
    }
  } else if (b < 5120) {
    // enc1 transpose -> E1T (out 1024 x 4096)
    const int b3 = b - 4096;
    const int c0 = (b3 & 15) * 64, r0 = (b3 >> 4) * 64;
#pragma unroll
    for (int it = 0; it < 4; ++it) {
      int idx = tid + it * 256;
      int r = idx >> 4, c4 = (idx & 15) * 4;
      float4 v = *(const float4*)&enc1[(long)(r0 + r) * 1024 + c0 + c4];
      t[c4 + 0][r] = v.x; t[c4 + 1][r] = v.y;
      t[c4 + 2][r] = v.z; t[c4 + 3][r] = v.w;
    }
    __syncthreads();
#pragma unroll
    for (int it = 0; it < 4; ++it) {
      int idx = tid + it * 256;
      int c = idx >> 4, r4 = (idx & 15) * 4;
      us4 o;
      o[0] = f2b(t[c][r4 + 0]); o[1] = f2b(t[c][r4 + 1]);
      o[2] = f2b(t[c][r4 + 2]); o[3] = f2b(t[c][r4 + 3]);
      *(us4*)&E1T[(long)(c0 + c) * 4096 + r0 + r4] = o;
    }
  } else {
    // weight transpose+convert
    const int b4 = b - 5120;
    const int x = b4 & 7, y = (b4 >> 3) & 7, z = b4 >> 6;
    const float* in = wp.p[z];
    const float s = wp.sc[z];
    unsigned short* ob = WT + (long)z * 262144;
    const int c0 = x * 64, r0 = y * 64;
#pragma unroll
    for (int it = 0; it < 4; ++it) {
      int idx = tid + it * 256;
      int r = idx >> 4, c4 = (idx & 15) * 4;
      float4 v = *(const float4*)&in[(long)(r0 + r) * 512 + c0 + c4];
      t[c4 + 0][r] = v.x; t[c4 + 1][r] = v.y;
      t[c4 + 2][r] = v.z; t[c4 + 3][r] = v.w;
    }
    __syncthreads();
#pragma unroll
    for (int it = 0; it < 4; ++it) {
      int idx = tid + it * 256;
      int c = idx >> 4, r4 = (idx & 15) * 4;
      us4 o;
      o[0] = f2b(t[c][r4 + 0] * s); o[1] = f2b(t[c][r4 + 1] * s);
      o[2] = f2b(t[c][r4 + 2] * s); o[3] = f2b(t[c][r4 + 3] * s);
      *(us4*)&ob[(long)(c0 + c) * 512 + r0 + r4] = o;
    }
  }
}

// ---------------------------------------------------------------------------
// prep stage B: combine 4 sub-window partials, write pooled^T bf16.
// ---------------------------------------------------------------------------
__global__ __launch_bounds__(256) void prep_finish(const float* __restrict__ S,
                                                   unsigned short* __restrict__ Pt) {
  const int t = blockIdx.x;   // 0..63
  const int cbi = blockIdx.y; // 0..3
  const int z = blockIdx.z;   // inp*4+n
  const int n = z & 3, inp = z >> 2;
  const int tid = threadIdx.x;
  __shared__ unsigned short sacc[64][20];
  const long sb = (((long)z * 16 + cbi * 4) * 64 + t) * 1024 + tid * 4;
  const float4 a = *(const float4*)&S[sb];
  const float4 b = *(const float4*)&S[sb + 65536];
  const float4 c = *(const float4*)&S[sb + 2 * 65536];
  const float4 d = *(const float4*)&S[sb + 3 * 65536];
  float acc[4];
  acc[0] = (a.x + b.x) + (c.x + d.x);
  acc[1] = (a.y + b.y) + (c.y + d.y);
  acc[2] = (a.z + b.z) + (c.z + d.z);
  acc[3] = (a.w + b.w) + (c.w + d.w);
  const int q = tid & 15, vb = tid >> 4;
#pragma unroll
  for (int j = 0; j < 4; ++j)
    sacc[q * 4 + j][vb] = f2b(acc[j] * (1.f / 16.f));
  __syncthreads();
  const int vvv = tid >> 2, iq = tid & 3;
  const us4 o = *(const us4*)&sacc[vvv][iq * 4];
  *(us4*)&Pt[(long)inp * (1L << 20) + (long)n * 262144 +
             (long)(vvv * 4 + cbi) * 1024 + t * 16 + iq * 4] = o;
}

// sum 4 bf16 split-K partials, convert to bf16. Grid-stride (1024 x 4).
__global__ __launch_bounds__(256) void addcvt4(const unsigned short* __restrict__ P,
                                               unsigned short* __restrict__ out) {
#pragma unroll
  for (int it = 0; it < 4; ++it) {
    const long i = ((long)(blockIdx.x + it * 1024) * 256 + threadIdx.x) * 4;
    const us4 a = *(const us4*)&P[i];
    const us4 b = *(const us4*)&P[i + 4194304];
    const us4 c = *(const us4*)&P[i + 2 * 4194304];
    const us4 d = *(const us4*)&P[i + 3 * 4194304];
    us4 o;
#pragma unroll
    for (int j = 0; j < 4; ++j)
      o[j] = f2b((b2f(a[j]) + b2f(b[j])) + (b2f(c[j]) + b2f(d[j])));
    *(us4*)&out[i] = o;
  }
}

// ---------------------------------------------------------------------------
// bf16 MFMA GEMM, 128x128 tile, BK=64, 4 waves; XOR-swizzled LDS.
// CMODE: 0 fp32; 1 bf16; 2 V^T layout; 3 C^T; 4 per-desc (mode==2 -> V^T).
// KSPLIT: s = bz%KSPLIT shifts A/B cols by s*K and C by s*sC2.
// ---------------------------------------------------------------------------
struct GDesc { const unsigned short* A; const unsigned short* B; long coff;
               const float* bias; int mode; float bscale; };
struct GDescs { GDesc d[16]; };

template <int ACT, int CMODE, int KSPLIT>
__global__ __launch_bounds__(256) void gemm_z(
    GDescs ga, void* __restrict__ Cv, int K, int lda, int ldb, int ldc,
    long sC2, float alpha) {
  const int bz = blockIdx.z;
  const int s = (KSPLIT > 1) ? (bz % KSPLIT) : 0;
  const int zb = (KSPLIT > 1) ? (bz / KSPLIT) : bz;
  const GDesc g = ga.d[zb];
  const unsigned short* Ab = g.A + (long)s * K;
  const unsigned short* Bb = g.B + (long)s * K;
  const int m0 = blockIdx.y * 128, n0 = blockIdx.x * 128;
  const int tid = threadIdx.x;
  const int lane = tid & 63, w = tid >> 6;
  const int wr = (w >> 1) * 64, wc = (w & 1) * 64;
  __shared__ unsigned short As[128 * 64];
  __shared__ unsigned short Bs[128 * 64];
  f32x4 acc[4][4];
#pragma unroll
  for (int i = 0; i < 4; ++i)
#pragma unroll
    for (int j = 0; j < 4; ++j) acc[i][j] = (f32x4){0.f, 0.f, 0.f, 0.f};
  const int srow = tid >> 3;
  const int scol = (((tid & 7) ^ ((tid >> 3) & 7)) << 3);
  const int rl = lane & 15, lg = lane >> 4, rx = rl & 7;
  for (int k0 = 0; k0 < K; k0 += 64) {
    __syncthreads();
#pragma unroll
    for (int it = 0; it < 4; ++it) {
      gload16(Ab + (long)(m0 + it * 32 + srow) * lda + k0 + scol,
              As + w * 512 + it * 2048);
      gload16(Bb + (long)(n0 + it * 32 + srow) * ldb + k0 + scol,
              Bs + w * 512 + it * 2048);
    }
    __syncthreads();
#pragma unroll
    for (int kk = 0; kk < 2; ++kk) {
      short8b af[4], bfr[4];
#pragma unroll
      for (int m = 0; m < 4; ++m)
        af[m] = *(const short8b*)&As[(wr + m * 16 + rl) * 64 +
                                     ((((kk * 4 + lg) ^ rx)) << 3)];
#pragma unroll
      for (int nn = 0; nn < 4; ++nn)
        bfr[nn] = *(const short8b*)&Bs[(wc + nn * 16 + rl) * 64 +
                                       ((((kk * 4 + lg) ^ rx)) << 3)];
#pragma unroll
      for (int m = 0; m < 4; ++m)
#pragma unroll
        for (int nn = 0; nn < 4; ++nn)
          acc[m][nn] = __builtin_amdgcn_mfma_f32_16x16x32_bf16(
              af[m], bfr[nn], acc[m][nn], 0, 0, 0);
    }
  }
  const int rrow = lg * 4;
  float bv[4];
#pragma unroll
  for (int nn = 0; nn < 4; ++nn)
    bv[nn] = g.bias ? g.bias[n0 + wc + nn * 16 + rl] * g.bscale : 0.f;
  const bool vt_layout = (CMODE == 2) || (CMODE == 4 && g.mode == 2);
  if (CMODE == 2 || CMODE == 4) {
    if (vt_layout) {
#pragma unroll
      for (int m = 0; m < 4; ++m)
#pragma unroll
        for (int nn = 0; nn < 4; ++nn) {
          const int row = m0 + wr + m * 16 + rrow;
          const int col = n0 + wc + nn * 16 + rl;
          us4 o;
#pragma unroll
          for (int r = 0; r < 4; ++r) {
            float v = alpha * acc[m][nn][r] + bv[nn];
            if (ACT == 1) v = LEAKY(v);
            o[r] = f2b(v);
          }
          const long off = g.coff + (long)(row >> 10) * 524288 +
                           (long)col * 1024 + (row & 1023);
          *(us4*)&((unsigned short*)Cv)[off] = o;
        }
    } else {
#pragma unroll
      for (int m = 0; m < 4; ++m)
#pragma unroll
        for (int nn = 0; nn < 4; ++nn)
#pragma unroll
          for (int r = 0; r < 4; ++r) {
            float v = alpha * acc[m][nn][r] + bv[nn];
            if (ACT == 1) v = LEAKY(v);
            const long off = g.coff +
                             (long)(m0 + wr + m * 16 + rrow + r) * ldc + n0 +
                             wc + nn * 16 + rl;
            ((unsigned short*)Cv)[off] = f2b(v);
          }
    }
  } else if (CMODE == 3) {
#pragma unroll
    for (int m = 0; m < 4; ++m)
#pragma unroll
      for (int nn = 0; nn < 4; ++nn) {
        const int row = m0 + wr + m * 16 + rrow;
        const int col = n0 + wc + nn * 16 + rl;
        us4 o;
#pragma unroll
        for (int r = 0; r < 4; ++r) {
          float v = alpha * acc[m][nn][r] + bv[nn];
          if (ACT == 1) v = LEAKY(v);
          o[r] = f2b(v);
        }
        *(us4*)&((unsigned short*)Cv)[g.coff + (long)col * ldc + row] = o;
      }
  } else {
#pragma unroll
    for (int m = 0; m < 4; ++m)
#pragma unroll
      for (int nn = 0; nn < 4; ++nn)
#pragma unroll
        for (int r = 0; r < 4; ++r) {
          float v = alpha * acc[m][nn][r] + bv[nn];
          if (ACT == 1) v = LEAKY(v);
          long off = g.coff + (long)s * sC2 +
                     (long)(m0 + wr + m * 16 + rrow + r) * ldc + n0 + wc +
                     nn * 16 + rl;
          if (CMODE == 1)
            ((unsigned short*)Cv)[off] = f2b(v);
          else
            ((float*)Cv)[off] = v;
        }
  }
}

// ---------------------------------------------------------------------------
// Fused BatchNorm on h^T (512 features x 16384 samples), bf16, in-place.
// ---------------------------------------------------------------------------
__global__ __launch_bounds__(256) void bn_fused(
    unsigned short* __restrict__ X,
    const float* __restrict__ g1, const float* __restrict__ be1,
    const float* __restrict__ g2, const float* __restrict__ be2) {
  const int f = blockIdx.x;
  const int z = blockIdx.z;
  unsigned short* p = X + (long)z * (8L << 20) + (long)f * 16384;
  const int tid = threadIdx.x;
  us4 v[16];
  float s = 0.f, q = 0.f;
#pragma unroll
  for (int k = 0; k < 16; ++k) {
    v[k] = *(const us4*)&p[(k * 256 + tid) * 4];
#pragma unroll
    for (int j = 0; j < 4; ++j) {
      const float x = b2f(v[k][j]);
      s += x; q += x * x;
    }
  }
#pragma unroll
  for (int mask = 1; mask < 64; mask <<= 1) {
    s += __shfl_xor(s, mask, 64);
    q += __shfl_xor(q, mask, 64);
  }
  __shared__ float rs[8];
  const int wv = tid >> 6;
  if ((tid & 63) == 0) { rs[wv] = s; rs[4 + wv] = q; }
  __syncthreads();
  s = rs[0] + rs[1] + rs[2] + rs[3];
  q = rs[4] + rs[5] + rs[6] + rs[7];
  const float mu = s * (1.f / 16384.f);
  const float var = q * (1.f / 16384.f) - mu * mu;
  const float gg = (z ? g2 : g1)[f];
  const float bb0 = (z ? be2 : be1)[f];
  const float rstd = rsqrtf(var + 1e-5f) * gg;
  const float bb = bb0 - mu * rstd;
#pragma unroll
  for (int k = 0; k < 16; ++k) {
    us4 o;
#pragma unroll
    for (int j = 0; j < 4; ++j) {
      const float y = b2f(v[k][j]) * rstd + bb;
      o[j] = f2b(LEAKY(y));
    }
    *(us4*)&p[(k * 256 + tid) * 4] = o;
  }
}

// ---------------------------------------------------------------------------
// bf16 MFMA flash attention, both attentions in one dispatch (z = 8).
// NO-MAX softmax (Q pre-scaled to log2 domain); Q fragments hoisted to regs.
// ---------------------------------------------------------------------------
__global__ __launch_bounds__(256) void attn_mfma(
    const unsigned short* __restrict__ Q, const unsigned short* __restrict__ K,
    const unsigned short* __restrict__ Vt, unsigned short* __restrict__ O) {
  const int qb = blockIdx.x, h = blockIdx.y;
  const int n = blockIdx.z & 3, sel = blockIdx.z >> 2;
  Q += (long)sel * 4194304;
  K += (long)sel * 4194304;
  Vt += (long)sel * 2097152;
  O += (long)sel * 2097152;
  const int tid = threadIdx.x;
  const int lane = tid & 63, w = tid >> 6;
  const int rl = lane & 15, lg = lane >> 4;
  __shared__ unsigned short Qs[4096];
  __shared__ unsigned short Ks[4096];
  __shared__ unsigned short Vs[4096];
  __shared__ unsigned short Ps[4096];
  stage64(Q + ((long)n * 1024 + qb * 64) * 512 + h * 64, 512, Qs, lane, w);
  __syncthreads();
  const int q = w * 16 + rl;
  const short8b qr0 = ldsw(Qs, q, lg);
  const short8b qr1 = ldsw(Qs, q, 4 + lg);
  float l_r = 0.f;
  f32x4 po[4];
#pragma unroll
  for (int i = 0; i < 4; ++i) po[i] = (f32x4){0.f, 0.f, 0.f, 0.f};
  const unsigned short* Kg0 = K + ((long)n * 1024) * 512 + h * 64;
  const unsigned short* Vg0 = Vt + (long)n * 524288 + (long)(h * 64) * 1024;
  for (int kt = 0; kt < 16; ++kt) {
    __syncthreads();
    stage64(Kg0 + (long)(kt * 64) * 512, 512, Ks, lane, w);
    stage64(Vg0 + kt * 64, 1024, Vs, lane, w);
    __syncthreads();
    f32x4 sa[4];
#pragma unroll
    for (int i = 0; i < 4; ++i) sa[i] = (f32x4){0.f, 0.f, 0.f, 0.f};
#pragma unroll
    for (int kk = 0; kk < 2; ++kk) {
      const short8b qf = kk ? qr1 : qr0;
#pragma unroll
      for (int mt = 0; mt < 4; ++mt) {
        const short8b kf = ldsw(Ks, mt * 16 + rl, 4 * kk + lg);
        sa[mt] = __builtin_amdgcn_mfma_f32_16x16x32_bf16(kf, qf, sa[mt], 0, 0, 0);
      }
    }
    float ps = 0.f;
#pragma unroll
    for (int mt = 0; mt < 4; ++mt) {
      us4 o;
#pragma unroll
      for (int r = 0; r < 4; ++r) {
        const float p = exp2f(sa[mt][r]);
        ps += p;
        o[r] = f2b(p);
      }
      const int c16 = (4 * mt + lg) >> 1;
      *(us4*)&Ps[q * 64 + ((c16 ^ (q & 7)) << 3) + ((lg & 1) << 2)] = o;
    }
    ps += __shfl_xor(ps, 16, 64);
    ps += __shfl_xor(ps, 32, 64);
    l_r += ps;
#pragma unroll
    for (int kk = 0; kk < 2; ++kk) {
      const short8b pf = ldsw(Ps, q, 4 * kk + lg);
#pragma unroll
      for (int nt = 0; nt < 4; ++nt) {
        const short8b vf = ldsw(Vs, nt * 16 + rl, 4 * kk + lg);
        po[nt] = __builtin_amdgcn_mfma_f32_16x16x32_bf16(pf, vf, po[nt], 0, 0, 0);
      }
    }
  }
  float invr[4];
#pragma unroll
  for (int r = 0; r < 4; ++r) invr[r] = 1.f / __shfl(l_r, lg * 4 + r, 64);
  const long ob = ((long)n * 1024 + qb * 64 + w * 16) * 512 + h * 64;
#pragma unroll
  for (int nt = 0; nt < 4; ++nt)
#pragma unroll
    for (int r = 0; r < 4; ++r)
      O[ob + (long)(lg * 4 + r) * 512 + nt * 16 + rl] = f2b(po[nt][r] * invr[r]);
}

// ---------------------------------------------------------------------------
// Softmax pass 1: per-row max & 1/sum, plus column sums of softmax(A).
// ---------------------------------------------------------------------------
__global__ __launch_bounds__(256) void softmax_cs(const float* __restrict__ D,
                                                  float* __restrict__ RS,
                                                  float* __restrict__ CS) {
  __shared__ float colacc[2048];
  __shared__ float red[8];
  const int tid = threadIdx.x;
  const int wv = tid >> 6, ln = tid & 63;
#pragma unroll
  for (int k = 0; k < 8; ++k) colacc[tid + k * 256] = 0.f;
  __syncthreads();
  const int r0 = blockIdx.x * 8;
  const int n = r0 >> 11;
  for (int rr = 0; rr < 8; ++rr) {
    const float* p = D + (long)(r0 + rr) * 2048;
    float v[8];
    float mx = -1e30f;
#pragma unroll
    for (int k = 0; k < 8; ++k) {
      v[k] = p[tid + k * 256];
      mx = fmaxf(mx, v[k]);
    }
#pragma unroll
    for (int mask = 1; mask < 64; mask <<= 1) mx = fmaxf(mx, __shfl_xor(mx, mask, 64));
    if (ln == 0) red[wv] = mx;
    __syncthreads();
    mx = fmaxf(fmaxf(red[0], red[1]), fmaxf(red[2], red[3]));
    float sum = 0.f;
#pragma unroll
    for (int k = 0; k < 8; ++k) {
      v[k] = __expf(v[k] - mx);
      sum += v[k];
    }
#pragma unroll
    for (int mask = 1; mask < 64; mask <<= 1) sum += __shfl_xor(sum, mask, 64);
    if (ln == 0) red[4 + wv] = sum;
    __syncthreads();
    sum = red[4] + red[5] + red[6] + red[7];
    const float inv = 1.f / sum;
    if (tid == 0) {
      RS[(r0 + rr) * 2] = mx;
      RS[(r0 + rr) * 2 + 1] = inv;
    }
#pragma unroll
    for (int k = 0; k < 8; ++k) colacc[tid + k * 256] += v[k] * inv;
    __syncthreads();
  }
#pragma unroll
  for (int k = 0; k < 8; ++k)
    atomicAdd(&CS[n * 2048 + tid + k * 256], colacc[tid + k * 256]);
}

// Pass 2: recompute softmax, apply column normalize. Grid-stride (2048 x 8).
__global__ __launch_bounds__(256) void final_scale(float* __restrict__ D,
                                                   const float* __restrict__ RS,
                                                   const float* __restrict__ CS) {
#pragma unroll
  for (int it = 0; it < 8; ++it) {
    const long i = ((long)(blockIdx.x + it * 2048) * 256 + threadIdx.x) * 4;
    const long row = i >> 11;
    const int n = (int)(row >> 11);
    const int j = (int)(i & 2047);
    const float mx = RS[row * 2];
    const float inv = RS[row * 2 + 1];
    float4 v = *(float4*)&D[i];
    const float* c = &CS[n * 2048 + j];
    v.x = __expf(v.x - mx) * inv * (c[0] > 0.f ? 1.f / c[0] : 0.f);
    v.y = __expf(v.y - mx) * inv * (c[1] > 0.f ? 1.f / c[1] : 0.f);
    v.z = __expf(v.z - mx) * inv * (c[2] > 0.f ? 1.f / c[2] : 0.f);
    v.w = __expf(v.w - mx) * inv * (c[3] > 0.f ? 1.f / c[3] : 0.f);
    *(float4*)&D[i] = v;
  }
}

// ---------------------------------------------------------------------------
extern "C" void kernel_launch(void* const* d_in, const int* in_sizes, int n_in,
                              void* d_out, int out_size, void* d_ws,
                              size_t ws_size, hipStream_t stream) {
  const float* x1 = (const float*)d_in[0];
  const float* x2 = (const float*)d_in[1];
  const float* enc1 = (const float*)d_in[2];
  const float* enc2 = (const float*)d_in[3];
  const float* mlp_b1 = (const float*)d_in[5];
  const float* mlp_b2 = (const float*)d_in[7];
  const float* mlp_g = (const float*)d_in[8];
  const float* mlp_be = (const float*)d_in[9];
  const float* nlp_b1 = (const float*)d_in[11];
  const float* nlp_b2 = (const float*)d_in[13];
  const float* nlp_g = (const float*)d_in[14];
  const float* nlp_be = (const float*)d_in[15];
  float* out = (float*)d_out;

  unsigned short* W = (unsigned short*)d_ws;
  const long M1 = 1L << 20;
  const long S = 262144;
  const float K2 = 0.18033688f;  // 0.125 * log2(e)
  // Rolling layout (us units), lifetimes disjoint-in-time (R6 audit + R9):
  unsigned short* Pt = W;
  unsigned short* ENC = W + 4 * M1;
  unsigned short* E1T = W + 12 * M1;
  unsigned short* WT = W + 16 * M1;
  unsigned short* NE = W + 20 * M1;
  unsigned short* H1T = W + 20 * M1;
  unsigned short* MID = W + 36 * M1;
  float* Sprep = (float*)(W + 36 * M1);
  unsigned short* PB = W + 36 * M1;   // edge bf16 split-K partials (16M us)
  unsigned short* E1 = W + 4 * M1;
  unsigned short* E2 = W + 6 * M1;
  unsigned short* QKV = W + 36 * M1;
  unsigned short* VT = W + 44 * M1;
  unsigned short* AO = W + 48 * M1;
  unsigned short* A1P = W + 8 * M1;
  unsigned short* A2P = W + 10 * M1;
  float* ST = (float*)(W + 56 * M1);
  float* CS = ST + 2048;
  float* RS = CS + 8192;

  const dim3 T(256);
  const long sP = 262144;
  const long sNE = 2097152;
  const long sE = 524288;
  const long sD = 4194304;

  // --- CS memset early (region dead until softmax) ---
  hipMemsetAsync(CS, 0, 8192 * sizeof(float), stream);

  // --- fused prologue (grid-stride) ---
  WPtrs wp;
  wp.p[0] = (const float*)d_in[4];   wp.sc[0] = 1.f;   // mlp_w1
  wp.p[1] = (const float*)d_in[6];   wp.sc[1] = 1.f;   // mlp_w2
  wp.p[2] = (const float*)d_in[10];  wp.sc[2] = 1.f;   // nlp_w1
  wp.p[3] = (const float*)d_in[12];  wp.sc[3] = 1.f;   // nlp_w2
  wp.p[4] = (const float*)d_in[16];  wp.sc[4] = K2;    // a1_wq (log2-scaled)
  wp.p[5] = (const float*)d_in[18];  wp.sc[5] = 1.f;   // a1_wk
  wp.p[6] = (const float*)d_in[24];  wp.sc[6] = K2;    // a2_wq (log2-scaled)
  wp.p[7] = (const float*)d_in[26];  wp.sc[7] = 1.f;   // a2_wk
  wp.p[8] = (const float*)d_in[20];  wp.sc[8] = 1.f;   // a1_wv
  wp.p[9] = (const float*)d_in[28];  wp.sc[9] = 1.f;   // a2_wv
  wp.p[10] = (const float*)d_in[22]; wp.sc[10] = 1.f;  // a1_fc
  wp.p[11] = (const float*)d_in[30]; wp.sc[11] = 1.f;  // a2_fc
  prologue_misc<<<5888, T, 0, stream>>>(x1, x2, Sprep, enc1, enc2, ENC, E1T,
                                        wp, WT);
  prep_finish<<<dim3(64, 4, 8), T, 0, stream>>>(Sprep, Pt);

  // --- node_enc for BOTH branches: z=16 (inp x pr x n) -> NE ---
  {
    GDescs g{};
    for (int inp = 0; inp < 2; ++inp)
      for (int pr = 0; pr < 2; ++pr)
        for (int nn = 0; nn < 4; ++nn)
          g.d[inp * 8 + pr * 4 + nn] = {
              ENC + (long)pr * (4 * M1), Pt + (long)inp * M1 + nn * sP,
              (long)inp * (8 * M1) + (long)nn * sNE + pr * 256, nullptr, 0, 1.f};
    gemm_z<0, 1, 1><<<dim3(2, 32, 16), T, 0, stream>>>(g, NE, 1024, 1024,
                                                       1024, 512, 0, 1.f);
  }
  // --- lin1 both branches (z=2) -> MID ---
  {
    GDescs g{};
    g.d[0] = {NE, WT + 0 * S, 0, mlp_b1, 0, 1.f};
    g.d[1] = {NE + 8 * M1, WT + 2 * S, 8 * M1, nlp_b1, 0, 1.f};
    gemm_z<1, 1, 1><<<dim3(4, 128, 2), T, 0, stream>>>(g, MID, 512, 512, 512,
                                                       512, 0, 1.f);
  }
  // --- lin2^T both branches (z=2) -> H1T/H2T (over NE, dead) ---
  {
    GDescs g{};
    g.d[0] = {MID, WT + 1 * S, 0, mlp_b2, 0, 1.f};
    g.d[1] = {MID + 8 * M1, WT + 3 * S, 8 * M1, nlp_b2, 0, 1.f};
    gemm_z<0, 3, 1><<<dim3(4, 128, 2), T, 0, stream>>>(g, H1T, 512, 512, 512,
                                                       16384, 0, 1.f);
  }
  bn_fused<<<dim3(512, 1, 2), T, 0, stream>>>(H1T, mlp_g, mlp_be, nlp_g, nlp_be);

  // --- edge decode: z = 8 descs x split-K 4, bf16 partials in MID region ---
  {
    GDescs g{};
    for (int d = 0; d < 8; ++d)
      g.d[d] = {E1T, H1T + (long)(d >> 2) * (8 * M1) + (d & 3) * 4096,
                (long)d * 524288, nullptr, 0, 1.f};
    gemm_z<0, 1, 4><<<dim3(4, 8, 32), T, 0, stream>>>(g, PB, 1024, 4096,
                                                      16384, 512, 4194304,
                                                      1.f / 1024.f);
  }
  addcvt4<<<1024, T, 0, stream>>>(PB, E1);

  // --- projections: Q1,K1,Q2,K2,V1,V2 in ONE dispatch (z=6, per-desc mode) ---
  {
    GDescs g{};
    g.d[0] = {E2, WT + 4 * S, 0, (const float*)d_in[17], 1, K2};
    g.d[1] = {E1, WT + 5 * S, 2 * M1, (const float*)d_in[19], 1, 1.f};
    g.d[2] = {E1, WT + 6 * S, 4 * M1, (const float*)d_in[25], 1, K2};
    g.d[3] = {E2, WT + 7 * S, 6 * M1, (const float*)d_in[27], 1, 1.f};
    g.d[4] = {E1, WT + 8 * S, 8 * M1, (const float*)d_in[21], 2, 1.f};
    g.d[5] = {E2, WT + 9 * S, 10 * M1, (const float*)d_in[29], 2, 1.f};
    gemm_z<0, 4, 1><<<dim3(4, 32, 6), T, 0, stream>>>(g, QKV, 512, 512, 512,
                                                      512, 0, 1.f);
  }

  // --- both attentions ---
  attn_mfma<<<dim3(16, 8, 8), T, 0, stream>>>(QKV, QKV + 2 * M1, VT, AO);

  // --- fc for both attentions -> A1P/A2P ---
  {
    GDescs g{};
    g.d[0] = {AO, WT + 10 * S, 0, (const float*)d_in[23], 0, 1.f};
    g.d[1] = {AO + 2 * M1, WT + 11 * S, 2 * M1, (const float*)d_in[31], 0, 1.f};
    gemm_z<0, 1, 1><<<dim3(4, 32, 2), T, 0, stream>>>(g, A1P, 512, 512, 512,
                                                      512, 0, 1.f);
  }

  // --- logits: all 4 quadrants x 4 n in one dispatch (z=16) ---
  {
    GDescs g{};
    for (int q = 0; q < 4; ++q)
      for (int n = 0; n < 4; ++n) {
        const unsigned short* A = (q < 2 ? A1P : A2P) + n * sE;
        const unsigned short* B = ((q == 0 || q == 2) ? A2P : A1P) + n * sE;
        const long coff =
            (long)n * sD + (q & 1) * 1024 + (long)(q >> 1) * 2097152;
        g.d[q * 4 + n] = {A, B, coff, nullptr, 0, 1.f};
      }
    gemm_z<0, 0, 1><<<dim3(8, 8, 16), T, 0, stream>>>(g, out, 512, 512, 512,
                                                      2048, 0, 1.f);
  }

  // --- softmax + column normalization (2 passes, no middle write) ---
  softmax_cs<<<1024, T, 0, stream>>>(out, RS, CS);
  final_scale<<<2048, T, 0, stream>>>(out, RS, CS);
}

// Round 13
// 378.988 us; speedup vs baseline: 1.0109x; 1.0096x over previous
//
#include <hip/hip_runtime.h>
#include <hip/hip_bf16.h>

#define LEAKY(v) ((v) >= 0.f ? (v) : 0.01f * (v))

typedef __attribute__((ext_vector_type(8))) short short8b;
typedef __attribute__((ext_vector_type(4))) float f32x4;
typedef __attribute__((ext_vector_type(4))) unsigned short us4;

__device__ __forceinline__ unsigned short f2b(float f) {
  unsigned int u = __builtin_bit_cast(unsigned int, f);
  return (unsigned short)((u + 0x7FFFu + ((u >> 16) & 1u)) >> 16);
}
__device__ __forceinline__ float b2f(unsigned short s) {
  return __builtin_bit_cast(float, (unsigned int)s << 16);
}

__device__ __forceinline__ void gload16(const unsigned short* g, unsigned short* l) {
  __builtin_amdgcn_global_load_lds(
      (const __attribute__((address_space(1))) unsigned int*)(g),
      (__attribute__((address_space(3))) unsigned int*)(l), 16, 0, 0);
}

// Stage a 64x64 bf16 tile (rows of 128B) global->LDS, XOR-swizzled source.
__device__ __forceinline__ void stage64(const unsigned short* g, int ldg,
                                        unsigned short* lds, int lane, int w) {
  const int r8 = lane >> 3;
  const int ce = ((lane & 7) ^ r8) << 3;
  const int r0 = w * 8 + r8;
  gload16(g + (long)r0 * ldg + ce, lds + w * 512);
  gload16(g + (long)(r0 + 32) * ldg + ce, lds + 2048 + w * 512);
}

// Swizzled 16B read: row, c4 = 16B-column index 0..7
__device__ __forceinline__ short8b ldsw(const unsigned short* base, int row, int c4) {
  return *(const short8b*)&base[row * 64 + (((c4 ^ (row & 7)) << 3))];
}

// ---------------------------------------------------------------------------
// 1-stage prep + exact AdaptiveAvgPool1d -> pooled^T bf16.
// ILP fix: __launch_bounds__(256,4) gives a 128-VGPR budget; all 16 channel
// loads are hoisted into registers (64 VGPRs) so they issue back-to-back.
// Block (t 0..63, cbi 0..3, z = inp*4+n): 2048 blocks.
// Pt[inp][n][k][i], k = vvv*4 + cbi, i = t*16 + vb:
//   value = mean_{m<16} X[n, cbi*16+m, t, vb*64+vvv]
// ---------------------------------------------------------------------------
__global__ __launch_bounds__(256, 4) void prep_pool_t(
    const float* __restrict__ X1, const float* __restrict__ X2,
    unsigned short* __restrict__ Pt) {
  const int t = blockIdx.x;   // 0..63
  const int cbi = blockIdx.y; // 0..3
  const int n = blockIdx.z & 3, inp = blockIdx.z >> 2;
  const float* X = inp ? X2 : X1;
  const int tid = threadIdx.x;
  __shared__ unsigned short sacc[64][20];
  const long base0 = (((long)n * 64 + cbi * 16) * 64 + t) * 1024 + tid * 4;
  f32x4 v[16];
#pragma unroll
  for (int m = 0; m < 16; ++m)
    v[m] = *(const f32x4*)&X[base0 + (long)m * 65536];
  const int q = tid & 15, vb = tid >> 4;
#pragma unroll
  for (int j = 0; j < 4; ++j) {
    float s = ((v[0][j] + v[1][j]) + (v[2][j] + v[3][j])) +
              ((v[4][j] + v[5][j]) + (v[6][j] + v[7][j]));
    s += ((v[8][j] + v[9][j]) + (v[10][j] + v[11][j])) +
         ((v[12][j] + v[13][j]) + (v[14][j] + v[15][j]));
    sacc[q * 4 + j][vb] = f2b(s * (1.f / 16.f));
  }
  __syncthreads();
  const int vvv = tid >> 2, iq = tid & 3;
  const us4 o = *(const us4*)&sacc[vvv][iq * 4];
  *(us4*)&Pt[(long)inp * (1L << 20) + (long)n * 262144 +
             (long)(vvv * 4 + cbi) * 1024 + t * 16 + iq * 4] = o;
}

// ---------------------------------------------------------------------------
// fp32 -> bf16 convert, both encodes; 2048 blocks x 4 hoisted tiles (ILP).
// ---------------------------------------------------------------------------
__global__ __launch_bounds__(256, 4) void convert2_f2b(
    const float* __restrict__ i1, const float* __restrict__ i2,
    unsigned short* __restrict__ out) {
  const int tid = threadIdx.x;
  f32x4 v[4];
  long oidx[4];
#pragma unroll
  for (int it = 0; it < 4; ++it) {
    const int cb = blockIdx.x + it * 2048;   // 0..8191
    const int z = cb >> 12;
    const float* in = z ? i2 : i1;
    const long i = (long)(cb & 4095) * 256 + tid;
    v[it] = ((const f32x4*)in)[i];
    oidx[it] = (long)z * (1L << 20) + i;
  }
#pragma unroll
  for (int it = 0; it < 4; ++it) {
    us4 q;
    q[0] = f2b(v[it][0]); q[1] = f2b(v[it][1]);
    q[2] = f2b(v[it][2]); q[3] = f2b(v[it][3]);
    ((us4*)out)[oidx[it]] = q;
  }
}

// ---------------------------------------------------------------------------
// fp32 (R x C) -> bf16 (C x R) transpose (enc1 -> E1T)
// ---------------------------------------------------------------------------
__global__ __launch_bounds__(256) void transpose_f2b(
    const float* __restrict__ in, unsigned short* __restrict__ out, int R, int C) {
  __shared__ float t[64][65];
  const int c0 = blockIdx.x * 64, r0 = blockIdx.y * 64;
  const int tid = threadIdx.x;
#pragma unroll
  for (int it = 0; it < 4; ++it) {
    int idx = tid + it * 256;
    int r = idx >> 4, c4 = (idx & 15) * 4;
    float4 v = *(const float4*)&in[(long)(r0 + r) * C + c0 + c4];
    t[c4 + 0][r] = v.x; t[c4 + 1][r] = v.y;
    t[c4 + 2][r] = v.z; t[c4 + 3][r] = v.w;
  }
  __syncthreads();
#pragma unroll
  for (int it = 0; it < 4; ++it) {
    int idx = tid + it * 256;
    int c = idx >> 4, r4 = (idx & 15) * 4;
    us4 o;
    o[0] = f2b(t[c][r4 + 0]); o[1] = f2b(t[c][r4 + 1]);
    o[2] = f2b(t[c][r4 + 2]); o[3] = f2b(t[c][r4 + 3]);
    *(us4*)&out[(long)(c0 + c) * R + r0 + r4] = o;
  }
}

// fused 12x 512x512 weight transpose+convert, per-slot scale
struct WPtrs { const float* p[12]; float sc[12]; };
__global__ __launch_bounds__(256) void wtrans(WPtrs wp, unsigned short* __restrict__ out) {
  const float* in = wp.p[blockIdx.z];
  const float s = wp.sc[blockIdx.z];
  unsigned short* ob = out + (long)blockIdx.z * 262144;
  __shared__ float t[64][65];
  const int c0 = blockIdx.x * 64, r0 = blockIdx.y * 64;
  const int tid = threadIdx.x;
#pragma unroll
  for (int it = 0; it < 4; ++it) {
    int idx = tid + it * 256;
    int r = idx >> 4, c4 = (idx & 15) * 4;
    float4 v = *(const float4*)&in[(long)(r0 + r) * 512 + c0 + c4];
    t[c4 + 0][r] = v.x; t[c4 + 1][r] = v.y;
    t[c4 + 2][r] = v.z; t[c4 + 3][r] = v.w;
  }
  __syncthreads();
#pragma unroll
  for (int it = 0; it < 4; ++it) {
    int idx = tid + it * 256;
    int c = idx >> 4, r4 = (idx & 15) * 4;
    us4 o;
    o[0] = f2b(t[c][r4 + 0] * s); o[1] = f2b(t[c][r4 + 1] * s);
    o[2] = f2b(t[c][r4 + 2] * s); o[3] = f2b(t[c][r4 + 3] * s);
    *(us4*)&ob[(long)(c0 + c) * 512 + r0 + r4] = o;
  }
}

// sum 4 bf16 split-K partials, convert to bf16. Grid-stride (1024 x 4).
__global__ __launch_bounds__(256) void addcvt4(const unsigned short* __restrict__ P,
                                               unsigned short* __restrict__ out) {
#pragma unroll
  for (int it = 0; it < 4; ++it) {
    const long i = ((long)(blockIdx.x + it * 1024) * 256 + threadIdx.x) * 4;
    const us4 a = *(const us4*)&P[i];
    const us4 b = *(const us4*)&P[i + 4194304];
    const us4 c = *(const us4*)&P[i + 2 * 4194304];
    const us4 d = *(const us4*)&P[i + 3 * 4194304];
    us4 o;
#pragma unroll
    for (int j = 0; j < 4; ++j)
      o[j] = f2b((b2f(a[j]) + b2f(b[j])) + (b2f(c[j]) + b2f(d[j])));
    *(us4*)&out[i] = o;
  }
}

// ---------------------------------------------------------------------------
// bf16 MFMA GEMM, 128x128 tile, BK=64, 4 waves; XOR-swizzled LDS.
// CMODE: 0 fp32; 1 bf16; 2 V^T layout; 3 C^T; 4 per-desc (mode==2 -> V^T).
// KSPLIT: s = bz%KSPLIT shifts A/B cols by s*K and C by s*sC2.
// ---------------------------------------------------------------------------
struct GDesc { const unsigned short* A; const unsigned short* B; long coff;
               const float* bias; int mode; float bscale; };
struct GDescs { GDesc d[16]; };

template <int ACT, int CMODE, int KSPLIT>
__global__ __launch_bounds__(256) void gemm_z(
    GDescs ga, void* __restrict__ Cv, int K, int lda, int ldb, int ldc,
    long sC2, float alpha) {
  const int bz = blockIdx.z;
  const int s = (KSPLIT > 1) ? (bz % KSPLIT) : 0;
  const int zb = (KSPLIT > 1) ? (bz / KSPLIT) : bz;
  const GDesc g = ga.d[zb];
  const unsigned short* Ab = g.A + (long)s * K;
  const unsigned short* Bb = g.B + (long)s * K;
  const int m0 = blockIdx.y * 128, n0 = blockIdx.x * 128;
  const int tid = threadIdx.x;
  const int lane = tid & 63, w = tid >> 6;
  const int wr = (w >> 1) * 64, wc = (w & 1) * 64;
  __shared__ unsigned short As[128 * 64];
  __shared__ unsigned short Bs[128 * 64];
  f32x4 acc[4][4];
#pragma unroll
  for (int i = 0; i < 4; ++i)
#pragma unroll
    for (int j = 0; j < 4; ++j) acc[i][j] = (f32x4){0.f, 0.f, 0.f, 0.f};
  const int srow = tid >> 3;
  const int scol = (((tid & 7) ^ ((tid >> 3) & 7)) << 3);
  const int rl = lane & 15, lg = lane >> 4, rx = rl & 7;
  for (int k0 = 0; k0 < K; k0 += 64) {
    __syncthreads();
#pragma unroll
    for (int it = 0; it < 4; ++it) {
      gload16(Ab + (long)(m0 + it * 32 + srow) * lda + k0 + scol,
              As + w * 512 + it * 2048);
      gload16(Bb + (long)(n0 + it * 32 + srow) * ldb + k0 + scol,
              Bs + w * 512 + it * 2048);
    }
    __syncthreads();
#pragma unroll
    for (int kk = 0; kk < 2; ++kk) {
      short8b af[4], bfr[4];
#pragma unroll
      for (int m = 0; m < 4; ++m)
        af[m] = *(const short8b*)&As[(wr + m * 16 + rl) * 64 +
                                     ((((kk * 4 + lg) ^ rx)) << 3)];
#pragma unroll
      for (int nn = 0; nn < 4; ++nn)
        bfr[nn] = *(const short8b*)&Bs[(wc + nn * 16 + rl) * 64 +
                                       ((((kk * 4 + lg) ^ rx)) << 3)];
#pragma unroll
      for (int m = 0; m < 4; ++m)
#pragma unroll
        for (int nn = 0; nn < 4; ++nn)
          acc[m][nn] = __builtin_amdgcn_mfma_f32_16x16x32_bf16(
              af[m], bfr[nn], acc[m][nn], 0, 0, 0);
    }
  }
  const int rrow = lg * 4;
  float bv[4];
#pragma unroll
  for (int nn = 0; nn < 4; ++nn)
    bv[nn] = g.bias ? g.bias[n0 + wc + nn * 16 + rl] * g.bscale : 0.f;
  const bool vt_layout = (CMODE == 2) || (CMODE == 4 && g.mode == 2);
  if (CMODE == 2 || CMODE == 4) {
    if (vt_layout) {
#pragma unroll
      for (int m = 0; m < 4; ++m)
#pragma unroll
        for (int nn = 0; nn < 4; ++nn) {
          const int row = m0 + wr + m * 16 + rrow;
          const int col = n0 + wc + nn * 16 + rl;
          us4 o;
#pragma unroll
          for (int r = 0; r < 4; ++r) {
            float v = alpha * acc[m][nn][r] + bv[nn];
            if (ACT == 1) v = LEAKY(v);
            o[r] = f2b(v);
          }
          const long off = g.coff + (long)(row >> 10) * 524288 +
                           (long)col * 1024 + (row & 1023);
          *(us4*)&((unsigned short*)Cv)[off] = o;
        }
    } else {
#pragma unroll
      for (int m = 0; m < 4; ++m)
#pragma unroll
        for (int nn = 0; nn < 4; ++nn)
#pragma unroll
          for (int r = 0; r < 4; ++r) {
            float v = alpha * acc[m][nn][r] + bv[nn];
            if (ACT == 1) v = LEAKY(v);
            const long off = g.coff +
                             (long)(m0 + wr + m * 16 + rrow + r) * ldc + n0 +
                             wc + nn * 16 + rl;
            ((unsigned short*)Cv)[off] = f2b(v);
          }
    }
  } else if (CMODE == 3) {
#pragma unroll
    for (int m = 0; m < 4; ++m)
#pragma unroll
      for (int nn = 0; nn < 4; ++nn) {
        const int row = m0 + wr + m * 16 + rrow;
        const int col = n0 + wc + nn * 16 + rl;
        us4 o;
#pragma unroll
        for (int r = 0; r < 4; ++r) {
          float v = alpha * acc[m][nn][r] + bv[nn];
          if (ACT == 1) v = LEAKY(v);
          o[r] = f2b(v);
        }
        *(us4*)&((unsigned short*)Cv)[g.coff + (long)col * ldc + row] = o;
      }
  } else {
#pragma unroll
    for (int m = 0; m < 4; ++m)
#pragma unroll
      for (int nn = 0; nn < 4; ++nn)
#pragma unroll
        for (int r = 0; r < 4; ++r) {
          float v = alpha * acc[m][nn][r] + bv[nn];
          if (ACT == 1) v = LEAKY(v);
          long off = g.coff + (long)s * sC2 +
                     (long)(m0 + wr + m * 16 + rrow + r) * ldc + n0 + wc +
                     nn * 16 + rl;
          if (CMODE == 1)
            ((unsigned short*)Cv)[off] = f2b(v);
          else
            ((float*)Cv)[off] = v;
        }
  }
}

// ---------------------------------------------------------------------------
// Fused BatchNorm on h^T (512 features x 16384 samples), bf16, in-place.
// ---------------------------------------------------------------------------
__global__ __launch_bounds__(256) void bn_fused(
    unsigned short* __restrict__ X,
    const float* __restrict__ g1, const float* __restrict__ be1,
    const float* __restrict__ g2, const float* __restrict__ be2) {
  const int f = blockIdx.x;
  const int z = blockIdx.z;
  unsigned short* p = X + (long)z * (8L << 20) + (long)f * 16384;
  const int tid = threadIdx.x;
  us4 v[16];
  float s = 0.f, q = 0.f;
#pragma unroll
  for (int k = 0; k < 16; ++k) {
    v[k] = *(const us4*)&p[(k * 256 + tid) * 4];
#pragma unroll
    for (int j = 0; j < 4; ++j) {
      const float x = b2f(v[k][j]);
      s += x; q += x * x;
    }
  }
#pragma unroll
  for (int mask = 1; mask < 64; mask <<= 1) {
    s += __shfl_xor(s, mask, 64);
    q += __shfl_xor(q, mask, 64);
  }
  __shared__ float rs[8];
  const int wv = tid >> 6;
  if ((tid & 63) == 0) { rs[wv] = s; rs[4 + wv] = q; }
  __syncthreads();
  s = rs[0] + rs[1] + rs[2] + rs[3];
  q = rs[4] + rs[5] + rs[6] + rs[7];
  const float mu = s * (1.f / 16384.f);
  const float var = q * (1.f / 16384.f) - mu * mu;
  const float gg = (z ? g2 : g1)[f];
  const float bb0 = (z ? be2 : be1)[f];
  const float rstd = rsqrtf(var + 1e-5f) * gg;
  const float bb = bb0 - mu * rstd;
#pragma unroll
  for (int k = 0; k < 16; ++k) {
    us4 o;
#pragma unroll
    for (int j = 0; j < 4; ++j) {
      const float y = b2f(v[k][j]) * rstd + bb;
      o[j] = f2b(LEAKY(y));
    }
    *(us4*)&p[(k * 256 + tid) * 4] = o;
  }
}

// ---------------------------------------------------------------------------
// bf16 MFMA flash attention, both attentions in one dispatch (z = 8).
// NO-MAX softmax (Q pre-scaled to log2 domain); Q fragments hoisted to regs.
// ---------------------------------------------------------------------------
__global__ __launch_bounds__(256) void attn_mfma(
    const unsigned short* __restrict__ Q, const unsigned short* __restrict__ K,
    const unsigned short* __restrict__ Vt, unsigned short* __restrict__ O) {
  const int qb = blockIdx.x, h = blockIdx.y;
  const int n = blockIdx.z & 3, sel = blockIdx.z >> 2;
  Q += (long)sel * 4194304;
  K += (long)sel * 4194304;
  Vt += (long)sel * 2097152;
  O += (long)sel * 2097152;
  const int tid = threadIdx.x;
  const int lane = tid & 63, w = tid >> 6;
  const int rl = lane & 15, lg = lane >> 4;
  __shared__ unsigned short Qs[4096];
  __shared__ unsigned short Ks[4096];
  __shared__ unsigned short Vs[4096];
  __shared__ unsigned short Ps[4096];
  stage64(Q + ((long)n * 1024 + qb * 64) * 512 + h * 64, 512, Qs, lane, w);
  __syncthreads();
  const int q = w * 16 + rl;
  const short8b qr0 = ldsw(Qs, q, lg);
  const short8b qr1 = ldsw(Qs, q, 4 + lg);
  float l_r = 0.f;
  f32x4 po[4];
#pragma unroll
  for (int i = 0; i < 4; ++i) po[i] = (f32x4){0.f, 0.f, 0.f, 0.f};
  const unsigned short* Kg0 = K + ((long)n * 1024) * 512 + h * 64;
  const unsigned short* Vg0 = Vt + (long)n * 524288 + (long)(h * 64) * 1024;
  for (int kt = 0; kt < 16; ++kt) {
    __syncthreads();
    stage64(Kg0 + (long)(kt * 64) * 512, 512, Ks, lane, w);
    stage64(Vg0 + kt * 64, 1024, Vs, lane, w);
    __syncthreads();
    f32x4 sa[4];
#pragma unroll
    for (int i = 0; i < 4; ++i) sa[i] = (f32x4){0.f, 0.f, 0.f, 0.f};
#pragma unroll
    for (int kk = 0; kk < 2; ++kk) {
      const short8b qf = kk ? qr1 : qr0;
#pragma unroll
      for (int mt = 0; mt < 4; ++mt) {
        const short8b kf = ldsw(Ks, mt * 16 + rl, 4 * kk + lg);
        sa[mt] = __builtin_amdgcn_mfma_f32_16x16x32_bf16(kf, qf, sa[mt], 0, 0, 0);
      }
    }
    float ps = 0.f;
#pragma unroll
    for (int mt = 0; mt < 4; ++mt) {
      us4 o;
#pragma unroll
      for (int r = 0; r < 4; ++r) {
        const float p = exp2f(sa[mt][r]);
        ps += p;
        o[r] = f2b(p);
      }
      const int c16 = (4 * mt + lg) >> 1;
      *(us4*)&Ps[q * 64 + ((c16 ^ (q & 7)) << 3) + ((lg & 1) << 2)] = o;
    }
    ps += __shfl_xor(ps, 16, 64);
    ps += __shfl_xor(ps, 32, 64);
    l_r += ps;
#pragma unroll
    for (int kk = 0; kk < 2; ++kk) {
      const short8b pf = ldsw(Ps, q, 4 * kk + lg);
#pragma unroll
      for (int nt = 0; nt < 4; ++nt) {
        const short8b vf = ldsw(Vs, nt * 16 + rl, 4 * kk + lg);
        po[nt] = __builtin_amdgcn_mfma_f32_16x16x32_bf16(pf, vf, po[nt], 0, 0, 0);
      }
    }
  }
  float invr[4];
#pragma unroll
  for (int r = 0; r < 4; ++r) invr[r] = 1.f / __shfl(l_r, lg * 4 + r, 64);
  const long ob = ((long)n * 1024 + qb * 64 + w * 16) * 512 + h * 64;
#pragma unroll
  for (int nt = 0; nt < 4; ++nt)
#pragma unroll
    for (int r = 0; r < 4; ++r)
      O[ob + (long)(lg * 4 + r) * 512 + nt * 16 + rl] = f2b(po[nt][r] * invr[r]);
}

// ---------------------------------------------------------------------------
// Softmax pass 1: per-row max & 1/sum, plus column sums of softmax(A).
// ---------------------------------------------------------------------------
__global__ __launch_bounds__(256) void softmax_cs(const float* __restrict__ D,
                                                  float* __restrict__ RS,
                                                  float* __restrict__ CS) {
  __shared__ float colacc[2048];
  __shared__ float red[8];
  const int tid = threadIdx.x;
  const int wv = tid >> 6, ln = tid & 63;
#pragma unroll
  for (int k = 0; k < 8; ++k) colacc[tid + k * 256] = 0.f;
  __syncthreads();
  const int r0 = blockIdx.x * 8;
  const int n = r0 >> 11;
  for (int rr = 0; rr < 8; ++rr) {
    const float* p = D + (long)(r0 + rr) * 2048;
    float v[8];
    float mx = -1e30f;
#pragma unroll
    for (int k = 0; k < 8; ++k) {
      v[k] = p[tid + k * 256];
      mx = fmaxf(mx, v[k]);
    }
#pragma unroll
    for (int mask = 1; mask < 64; mask <<= 1) mx = fmaxf(mx, __shfl_xor(mx, mask, 64));
    if (ln == 0) red[wv] = mx;
    __syncthreads();
    mx = fmaxf(fmaxf(red[0], red[1]), fmaxf(red[2], red[3]));
    float sum = 0.f;
#pragma unroll
    for (int k = 0; k < 8; ++k) {
      v[k] = __expf(v[k] - mx);
      sum += v[k];
    }
#pragma unroll
    for (int mask = 1; mask < 64; mask <<= 1) sum += __shfl_xor(sum, mask, 64);
    if (ln == 0) red[4 + wv] = sum;
    __syncthreads();
    sum = red[4] + red[5] + red[6] + red[7];
    const float inv = 1.f / sum;
    if (tid == 0) {
      RS[(r0 + rr) * 2] = mx;
      RS[(r0 + rr) * 2 + 1] = inv;
    }
#pragma unroll
    for (int k = 0; k < 8; ++k) colacc[tid + k * 256] += v[k] * inv;
    __syncthreads();
  }
#pragma unroll
  for (int k = 0; k < 8; ++k)
    atomicAdd(&CS[n * 2048 + tid + k * 256], colacc[tid + k * 256]);
}

// Pass 2: recompute softmax, apply column normalize. Grid-stride (2048 x 8).
__global__ __launch_bounds__(256) void final_scale(float* __restrict__ D,
                                                   const float* __restrict__ RS,
                                                   const float* __restrict__ CS) {
#pragma unroll
  for (int it = 0; it < 8; ++it) {
    const long i = ((long)(blockIdx.x + it * 2048) * 256 + threadIdx.x) * 4;
    const long row = i >> 11;
    const int n = (int)(row >> 11);
    const int j = (int)(i & 2047);
    const float mx = RS[row * 2];
    const float inv = RS[row * 2 + 1];
    float4 v = *(float4*)&D[i];
    const float* c = &CS[n * 2048 + j];
    v.x = __expf(v.x - mx) * inv * (c[0] > 0.f ? 1.f / c[0] : 0.f);
    v.y = __expf(v.y - mx) * inv * (c[1] > 0.f ? 1.f / c[1] : 0.f);
    v.z = __expf(v.z - mx) * inv * (c[2] > 0.f ? 1.f / c[2] : 0.f);
    v.w = __expf(v.w - mx) * inv * (c[3] > 0.f ? 1.f / c[3] : 0.f);
    *(float4*)&D[i] = v;
  }
}

// ---------------------------------------------------------------------------
extern "C" void kernel_launch(void* const* d_in, const int* in_sizes, int n_in,
                              void* d_out, int out_size, void* d_ws,
                              size_t ws_size, hipStream_t stream) {
  const float* x1 = (const float*)d_in[0];
  const float* x2 = (const float*)d_in[1];
  const float* enc1 = (const float*)d_in[2];
  const float* enc2 = (const float*)d_in[3];
  const float* mlp_b1 = (const float*)d_in[5];
  const float* mlp_b2 = (const float*)d_in[7];
  const float* mlp_g = (const float*)d_in[8];
  const float* mlp_be = (const float*)d_in[9];
  const float* nlp_b1 = (const float*)d_in[11];
  const float* nlp_b2 = (const float*)d_in[13];
  const float* nlp_g = (const float*)d_in[14];
  const float* nlp_be = (const float*)d_in[15];
  float* out = (float*)d_out;

  unsigned short* W = (unsigned short*)d_ws;
  const long M1 = 1L << 20;
  const long S = 262144;
  const float K2 = 0.18033688f;  // 0.125 * log2(e)
  // Rolling layout (us units), lifetimes disjoint-in-time:
  //  0.. 2M : Pt                               [dead after node_enc]
  //  4..12M : ENC -> E1/E2 (4..8M) -> A1P/A2P (8..12M)
  // 12..16M : E1T                              [dead after edge decode]
  // 16..19M : WT                               [dead after fc]
  // 20..36M : NE -> H1T/H2T                    [dead after edge decode]
  // 36..52M : MID (lin1) -> edge bf16 partials (16M us)
  //           -> QKQK (36..44M), V^T (44..48M), AO (48..52M)
  unsigned short* Pt = W;
  unsigned short* ENC = W + 4 * M1;
  unsigned short* E1T = W + 12 * M1;
  unsigned short* WT = W + 16 * M1;
  unsigned short* NE = W + 20 * M1;
  unsigned short* H1T = W + 20 * M1;
  unsigned short* MID = W + 36 * M1;
  unsigned short* PB = W + 36 * M1;   // edge bf16 split-K partials (16M us)
  unsigned short* E1 = W + 4 * M1;
  unsigned short* E2 = W + 6 * M1;
  unsigned short* QKV = W + 36 * M1;
  unsigned short* VT = W + 44 * M1;
  unsigned short* AO = W + 48 * M1;
  unsigned short* A1P = W + 8 * M1;
  unsigned short* A2P = W + 10 * M1;
  float* ST = (float*)(W + 56 * M1);
  float* CS = ST + 2048;
  float* RS = CS + 8192;

  const dim3 T(256);
  const long sP = 262144;
  const long sNE = 2097152;
  const long sE = 524288;
  const long sD = 4194304;

  // --- CS memset early (region dead until softmax) ---
  hipMemsetAsync(CS, 0, 8192 * sizeof(float), stream);

  // --- prologue: separate specialized kernels ---
  prep_pool_t<<<dim3(64, 4, 8), T, 0, stream>>>(x1, x2, Pt);
  convert2_f2b<<<2048, T, 0, stream>>>(enc1, enc2, ENC);
  transpose_f2b<<<dim3(16, 64), T, 0, stream>>>(enc1, E1T, 4096, 1024);
  WPtrs wp;
  wp.p[0] = (const float*)d_in[4];   wp.sc[0] = 1.f;   // mlp_w1
  wp.p[1] = (const float*)d_in[6];   wp.sc[1] = 1.f;   // mlp_w2
  wp.p[2] = (const float*)d_in[10];  wp.sc[2] = 1.f;   // nlp_w1
  wp.p[3] = (const float*)d_in[12];  wp.sc[3] = 1.f;   // nlp_w2
  wp.p[4] = (const float*)d_in[16];  wp.sc[4] = K2;    // a1_wq (log2-scaled)
  wp.p[5] = (const float*)d_in[18];  wp.sc[5] = 1.f;   // a1_wk
  wp.p[6] = (const float*)d_in[24];  wp.sc[6] = K2;    // a2_wq (log2-scaled)
  wp.p[7] = (const float*)d_in[26];  wp.sc[7] = 1.f;   // a2_wk
  wp.p[8] = (const float*)d_in[20];  wp.sc[8] = 1.f;   // a1_wv
  wp.p[9] = (const float*)d_in[28];  wp.sc[9] = 1.f;   // a2_wv
  wp.p[10] = (const float*)d_in[22]; wp.sc[10] = 1.f;  // a1_fc
  wp.p[11] = (const float*)d_in[30]; wp.sc[11] = 1.f;  // a2_fc
  wtrans<<<dim3(8, 8, 12), T, 0, stream>>>(wp, WT);

  // --- node_enc for BOTH branches: z=16 (inp x pr x n) -> NE ---
  {
    GDescs g{};
    for (int inp = 0; inp < 2; ++inp)
      for (int pr = 0; pr < 2; ++pr)
        for (int nn = 0; nn < 4; ++nn)
          g.d[inp * 8 + pr * 4 + nn] = {
              ENC + (long)pr * (4 * M1), Pt + (long)inp * M1 + nn * sP,
              (long)inp * (8 * M1) + (long)nn * sNE + pr * 256, nullptr, 0, 1.f};
    gemm_z<0, 1, 1><<<dim3(2, 32, 16), T, 0, stream>>>(g, NE, 1024, 1024,
                                                       1024, 512, 0, 1.f);
  }
  // --- lin1 both branches (z=2) -> MID ---
  {
    GDescs g{};
    g.d[0] = {NE, WT + 0 * S, 0, mlp_b1, 0, 1.f};
    g.d[1] = {NE + 8 * M1, WT + 2 * S, 8 * M1, nlp_b1, 0, 1.f};
    gemm_z<1, 1, 1><<<dim3(4, 128, 2), T, 0, stream>>>(g, MID, 512, 512, 512,
                                                       512, 0, 1.f);
  }
  // --- lin2^T both branches (z=2) -> H1T/H2T (over NE, dead) ---
  {
    GDescs g{};
    g.d[0] = {MID, WT + 1 * S, 0, mlp_b2, 0, 1.f};
    g.d[1] = {MID + 8 * M1, WT + 3 * S, 8 * M1, nlp_b2, 0, 1.f};
    gemm_z<0, 3, 1><<<dim3(4, 128, 2), T, 0, stream>>>(g, H1T, 512, 512, 512,
                                                       16384, 0, 1.f);
  }
  bn_fused<<<dim3(512, 1, 2), T, 0, stream>>>(H1T, mlp_g, mlp_be, nlp_g, nlp_be);

  // --- edge decode: z = 8 descs x split-K 4, bf16 partials in MID region ---
  {
    GDescs g{};
    for (int d = 0; d < 8; ++d)
      g.d[d] = {E1T, H1T + (long)(d >> 2) * (8 * M1) + (d & 3) * 4096,
                (long)d * 524288, nullptr, 0, 1.f};
    gemm_z<0, 1, 4><<<dim3(4, 8, 32), T, 0, stream>>>(g, PB, 1024, 4096,
                                                      16384, 512, 4194304,
                                                      1.f / 1024.f);
  }
  addcvt4<<<1024, T, 0, stream>>>(PB, E1);

  // --- projections: Q1,K1,Q2,K2,V1,V2 in ONE dispatch (z=6, per-desc mode) ---
  {
    GDescs g{};
    g.d[0] = {E2, WT + 4 * S, 0, (const float*)d_in[17], 1, K2};
    g.d[1] = {E1, WT + 5 * S, 2 * M1, (const float*)d_in[19], 1, 1.f};
    g.d[2] = {E1, WT + 6 * S, 4 * M1, (const float*)d_in[25], 1, K2};
    g.d[3] = {E2, WT + 7 * S, 6 * M1, (const float*)d_in[27], 1, 1.f};
    g.d[4] = {E1, WT + 8 * S, 8 * M1, (const float*)d_in[21], 2, 1.f};
    g.d[5] = {E2, WT + 9 * S, 10 * M1, (const float*)d_in[29], 2, 1.f};
    gemm_z<0, 4, 1><<<dim3(4, 32, 6), T, 0, stream>>>(g, QKV, 512, 512, 512,
                                                      512, 0, 1.f);
  }

  // --- both attentions ---
  attn_mfma<<<dim3(16, 8, 8), T, 0, stream>>>(QKV, QKV + 2 * M1, VT, AO);

  // --- fc for both attentions -> A1P/A2P ---
  {
    GDescs g{};
    g.d[0] = {AO, WT + 10 * S, 0, (const float*)d_in[23], 0, 1.f};
    g.d[1] = {AO + 2 * M1, WT + 11 * S, 2 * M1, (const float*)d_in[31], 0, 1.f};
    gemm_z<0, 1, 1><<<dim3(4, 32, 2), T, 0, stream>>>(g, A1P, 512, 512, 512,
                                                      512, 0, 1.f);
  }

  // --- logits: all 4 quadrants x 4 n in one dispatch (z=16) ---
  {
    GDescs g{};
    for (int q = 0; q < 4; ++q)
      for (int n = 0; n < 4; ++n) {
        const unsigned short* A = (q < 2 ? A1P : A2P) + n * sE;
        const unsigned short* B = ((q == 0 || q == 2) ? A2P : A1P) + n * sE;
        const long coff =
            (long)n * sD + (q & 1) * 1024 + (long)(q >> 1) * 2097152;
        g.d[q * 4 + n] = {A, B, coff, nullptr, 0, 1.f};
      }
    gemm_z<0, 0, 1><<<dim3(8, 8, 16), T, 0, stream>>>(g, out, 512, 512, 512,
                                                      2048, 0, 1.f);
  }

  // --- softmax + column normalization (2 passes, no middle write) ---
  softmax_cs<<<1024, T, 0, stream>>>(out, RS, CS);
  final_scale<<<2048, T, 0, stream>>>(out, RS, CS);
}

// Round 14
// 378.421 us; speedup vs baseline: 1.0124x; 1.0015x over previous
//
#include <hip/hip_runtime.h>
#include <hip/hip_bf16.h>

#define LEAKY(v) ((v) >= 0.f ? (v) : 0.01f * (v))

typedef __attribute__((ext_vector_type(8))) short short8b;
typedef __attribute__((ext_vector_type(4))) float f32x4;
typedef __attribute__((ext_vector_type(4))) unsigned short us4;

__device__ __forceinline__ unsigned short f2b(float f) {
  unsigned int u = __builtin_bit_cast(unsigned int, f);
  return (unsigned short)((u + 0x7FFFu + ((u >> 16) & 1u)) >> 16);
}
__device__ __forceinline__ float b2f(unsigned short s) {
  return __builtin_bit_cast(float, (unsigned int)s << 16);
}

__device__ __forceinline__ void gload16(const unsigned short* g, unsigned short* l) {
  __builtin_amdgcn_global_load_lds(
      (const __attribute__((address_space(1))) unsigned int*)(g),
      (__attribute__((address_space(3))) unsigned int*)(l), 16, 0, 0);
}

// Stage a 64x64 bf16 tile (rows of 128B) global->LDS, XOR-swizzled source.
__device__ __forceinline__ void stage64(const unsigned short* g, int ldg,
                                        unsigned short* lds, int lane, int w) {
  const int r8 = lane >> 3;
  const int ce = ((lane & 7) ^ r8) << 3;
  const int r0 = w * 8 + r8;
  gload16(g + (long)r0 * ldg + ce, lds + w * 512);
  gload16(g + (long)(r0 + 32) * ldg + ce, lds + 2048 + w * 512);
}

// Swizzled 16B read: row, c4 = 16B-column index 0..7
__device__ __forceinline__ short8b ldsw(const unsigned short* base, int row, int c4) {
  return *(const short8b*)&base[row * 64 + (((c4 ^ (row & 7)) << 3))];
}

// ---------------------------------------------------------------------------
// 1-stage prep + exact AdaptiveAvgPool1d -> pooled^T bf16 (ILP-hoisted).
// ---------------------------------------------------------------------------
__global__ __launch_bounds__(256, 4) void prep_pool_t(
    const float* __restrict__ X1, const float* __restrict__ X2,
    unsigned short* __restrict__ Pt) {
  const int t = blockIdx.x;   // 0..63
  const int cbi = blockIdx.y; // 0..3
  const int n = blockIdx.z & 3, inp = blockIdx.z >> 2;
  const float* X = inp ? X2 : X1;
  const int tid = threadIdx.x;
  __shared__ unsigned short sacc[64][20];
  const long base0 = (((long)n * 64 + cbi * 16) * 64 + t) * 1024 + tid * 4;
  f32x4 v[16];
#pragma unroll
  for (int m = 0; m < 16; ++m)
    v[m] = *(const f32x4*)&X[base0 + (long)m * 65536];
  const int q = tid & 15, vb = tid >> 4;
#pragma unroll
  for (int j = 0; j < 4; ++j) {
    float s = ((v[0][j] + v[1][j]) + (v[2][j] + v[3][j])) +
              ((v[4][j] + v[5][j]) + (v[6][j] + v[7][j]));
    s += ((v[8][j] + v[9][j]) + (v[10][j] + v[11][j])) +
         ((v[12][j] + v[13][j]) + (v[14][j] + v[15][j]));
    sacc[q * 4 + j][vb] = f2b(s * (1.f / 16.f));
  }
  __syncthreads();
  const int vvv = tid >> 2, iq = tid & 3;
  const us4 o = *(const us4*)&sacc[vvv][iq * 4];
  *(us4*)&Pt[(long)inp * (1L << 20) + (long)n * 262144 +
             (long)(vvv * 4 + cbi) * 1024 + t * 16 + iq * 4] = o;
}

// ---------------------------------------------------------------------------
// fp32 -> bf16 convert, both encodes; 2048 blocks x 4 hoisted tiles (ILP).
// ---------------------------------------------------------------------------
__global__ __launch_bounds__(256, 4) void convert2_f2b(
    const float* __restrict__ i1, const float* __restrict__ i2,
    unsigned short* __restrict__ out) {
  const int tid = threadIdx.x;
  f32x4 v[4];
  long oidx[4];
#pragma unroll
  for (int it = 0; it < 4; ++it) {
    const int cb = blockIdx.x + it * 2048;   // 0..8191
    const int z = cb >> 12;
    const float* in = z ? i2 : i1;
    const long i = (long)(cb & 4095) * 256 + tid;
    v[it] = ((const f32x4*)in)[i];
    oidx[it] = (long)z * (1L << 20) + i;
  }
#pragma unroll
  for (int it = 0; it < 4; ++it) {
    us4 q;
    q[0] = f2b(v[it][0]); q[1] = f2b(v[it][1]);
    q[2] = f2b(v[it][2]); q[3] = f2b(v[it][3]);
    ((us4*)out)[oidx[it]] = q;
  }
}

// ---------------------------------------------------------------------------
// fp32 (R x C) -> bf16 (C x R) transpose (enc1 -> E1T)
// ---------------------------------------------------------------------------
__global__ __launch_bounds__(256) void transpose_f2b(
    const float* __restrict__ in, unsigned short* __restrict__ out, int R, int C) {
  __shared__ float t[64][65];
  const int c0 = blockIdx.x * 64, r0 = blockIdx.y * 64;
  const int tid = threadIdx.x;
#pragma unroll
  for (int it = 0; it < 4; ++it) {
    int idx = tid + it * 256;
    int r = idx >> 4, c4 = (idx & 15) * 4;
    float4 v = *(const float4*)&in[(long)(r0 + r) * C + c0 + c4];
    t[c4 + 0][r] = v.x; t[c4 + 1][r] = v.y;
    t[c4 + 2][r] = v.z; t[c4 + 3][r] = v.w;
  }
  __syncthreads();
#pragma unroll
  for (int it = 0; it < 4; ++it) {
    int idx = tid + it * 256;
    int c = idx >> 4, r4 = (idx & 15) * 4;
    us4 o;
    o[0] = f2b(t[c][r4 + 0]); o[1] = f2b(t[c][r4 + 1]);
    o[2] = f2b(t[c][r4 + 2]); o[3] = f2b(t[c][r4 + 3]);
    *(us4*)&out[(long)(c0 + c) * R + r0 + r4] = o;
  }
}

// fused 12x 512x512 weight transpose+convert, per-slot scale
struct WPtrs { const float* p[12]; float sc[12]; };
__global__ __launch_bounds__(256) void wtrans(WPtrs wp, unsigned short* __restrict__ out) {
  const float* in = wp.p[blockIdx.z];
  const float s = wp.sc[blockIdx.z];
  unsigned short* ob = out + (long)blockIdx.z * 262144;
  __shared__ float t[64][65];
  const int c0 = blockIdx.x * 64, r0 = blockIdx.y * 64;
  const int tid = threadIdx.x;
#pragma unroll
  for (int it = 0; it < 4; ++it) {
    int idx = tid + it * 256;
    int r = idx >> 4, c4 = (idx & 15) * 4;
    float4 v = *(const float4*)&in[(long)(r0 + r) * 512 + c0 + c4];
    t[c4 + 0][r] = v.x; t[c4 + 1][r] = v.y;
    t[c4 + 2][r] = v.z; t[c4 + 3][r] = v.w;
  }
  __syncthreads();
#pragma unroll
  for (int it = 0; it < 4; ++it) {
    int idx = tid + it * 256;
    int c = idx >> 4, r4 = (idx & 15) * 4;
    us4 o;
    o[0] = f2b(t[c][r4 + 0] * s); o[1] = f2b(t[c][r4 + 1] * s);
    o[2] = f2b(t[c][r4 + 2] * s); o[3] = f2b(t[c][r4 + 3] * s);
    *(us4*)&ob[(long)(c0 + c) * 512 + r0 + r4] = o;
  }
}

// sum 4 bf16 split-K partials, convert to bf16. Grid-stride (1024 x 4).
__global__ __launch_bounds__(256) void addcvt4(const unsigned short* __restrict__ P,
                                               unsigned short* __restrict__ out) {
#pragma unroll
  for (int it = 0; it < 4; ++it) {
    const long i = ((long)(blockIdx.x + it * 1024) * 256 + threadIdx.x) * 4;
    const us4 a = *(const us4*)&P[i];
    const us4 b = *(const us4*)&P[i + 4194304];
    const us4 c = *(const us4*)&P[i + 2 * 4194304];
    const us4 d = *(const us4*)&P[i + 3 * 4194304];
    us4 o;
#pragma unroll
    for (int j = 0; j < 4; ++j)
      o[j] = f2b((b2f(a[j]) + b2f(b[j])) + (b2f(c[j]) + b2f(d[j])));
    *(us4*)&out[i] = o;
  }
}

// ---------------------------------------------------------------------------
// bf16 MFMA GEMM, 128x128 tile, BK=64, 4 waves; XOR-swizzled LDS.
// CMODE: 0 fp32; 1 bf16; 2 V^T layout; 3 C^T; 4 per-desc (mode==2 -> V^T).
// KSPLIT: s = bz%KSPLIT shifts A/B cols by s*K and C by s*sC2.
// ---------------------------------------------------------------------------
struct GDesc { const unsigned short* A; const unsigned short* B; long coff;
               const float* bias; int mode; float bscale; };
struct GDescs { GDesc d[16]; };

template <int ACT, int CMODE, int KSPLIT>
__global__ __launch_bounds__(256) void gemm_z(
    GDescs ga, void* __restrict__ Cv, int K, int lda, int ldb, int ldc,
    long sC2, float alpha) {
  const int bz = blockIdx.z;
  const int s = (KSPLIT > 1) ? (bz % KSPLIT) : 0;
  const int zb = (KSPLIT > 1) ? (bz / KSPLIT) : bz;
  const GDesc g = ga.d[zb];
  const unsigned short* Ab = g.A + (long)s * K;
  const unsigned short* Bb = g.B + (long)s * K;
  const int m0 = blockIdx.y * 128, n0 = blockIdx.x * 128;
  const int tid = threadIdx.x;
  const int lane = tid & 63, w = tid >> 6;
  const int wr = (w >> 1) * 64, wc = (w & 1) * 64;
  __shared__ unsigned short As[128 * 64];
  __shared__ unsigned short Bs[128 * 64];
  f32x4 acc[4][4];
#pragma unroll
  for (int i = 0; i < 4; ++i)
#pragma unroll
    for (int j = 0; j < 4; ++j) acc[i][j] = (f32x4){0.f, 0.f, 0.f, 0.f};
  const int srow = tid >> 3;
  const int scol = (((tid & 7) ^ ((tid >> 3) & 7)) << 3);
  const int rl = lane & 15, lg = lane >> 4, rx = rl & 7;
  for (int k0 = 0; k0 < K; k0 += 64) {
    __syncthreads();
#pragma unroll
    for (int it = 0; it < 4; ++it) {
      gload16(Ab + (long)(m0 + it * 32 + srow) * lda + k0 + scol,
              As + w * 512 + it * 2048);
      gload16(Bb + (long)(n0 + it * 32 + srow) * ldb + k0 + scol,
              Bs + w * 512 + it * 2048);
    }
    __syncthreads();
#pragma unroll
    for (int kk = 0; kk < 2; ++kk) {
      short8b af[4], bfr[4];
#pragma unroll
      for (int m = 0; m < 4; ++m)
        af[m] = *(const short8b*)&As[(wr + m * 16 + rl) * 64 +
                                     ((((kk * 4 + lg) ^ rx)) << 3)];
#pragma unroll
      for (int nn = 0; nn < 4; ++nn)
        bfr[nn] = *(const short8b*)&Bs[(wc + nn * 16 + rl) * 64 +
                                       ((((kk * 4 + lg) ^ rx)) << 3)];
#pragma unroll
      for (int m = 0; m < 4; ++m)
#pragma unroll
        for (int nn = 0; nn < 4; ++nn)
          acc[m][nn] = __builtin_amdgcn_mfma_f32_16x16x32_bf16(
              af[m], bfr[nn], acc[m][nn], 0, 0, 0);
    }
  }
  const int rrow = lg * 4;
  float bv[4];
#pragma unroll
  for (int nn = 0; nn < 4; ++nn)
    bv[nn] = g.bias ? g.bias[n0 + wc + nn * 16 + rl] * g.bscale : 0.f;
  const bool vt_layout = (CMODE == 2) || (CMODE == 4 && g.mode == 2);
  if (CMODE == 2 || CMODE == 4) {
    if (vt_layout) {
#pragma unroll
      for (int m = 0; m < 4; ++m)
#pragma unroll
        for (int nn = 0; nn < 4; ++nn) {
          const int row = m0 + wr + m * 16 + rrow;
          const int col = n0 + wc + nn * 16 + rl;
          us4 o;
#pragma unroll
          for (int r = 0; r < 4; ++r) {
            float v = alpha * acc[m][nn][r] + bv[nn];
            if (ACT == 1) v = LEAKY(v);
            o[r] = f2b(v);
          }
          const long off = g.coff + (long)(row >> 10) * 524288 +
                           (long)col * 1024 + (row & 1023);
          *(us4*)&((unsigned short*)Cv)[off] = o;
        }
    } else {
#pragma unroll
      for (int m = 0; m < 4; ++m)
#pragma unroll
        for (int nn = 0; nn < 4; ++nn)
#pragma unroll
          for (int r = 0; r < 4; ++r) {
            float v = alpha * acc[m][nn][r] + bv[nn];
            if (ACT == 1) v = LEAKY(v);
            const long off = g.coff +
                             (long)(m0 + wr + m * 16 + rrow + r) * ldc + n0 +
                             wc + nn * 16 + rl;
            ((unsigned short*)Cv)[off] = f2b(v);
          }
    }
  } else if (CMODE == 3) {
#pragma unroll
    for (int m = 0; m < 4; ++m)
#pragma unroll
      for (int nn = 0; nn < 4; ++nn) {
        const int row = m0 + wr + m * 16 + rrow;
        const int col = n0 + wc + nn * 16 + rl;
        us4 o;
#pragma unroll
        for (int r = 0; r < 4; ++r) {
          float v = alpha * acc[m][nn][r] + bv[nn];
          if (ACT == 1) v = LEAKY(v);
          o[r] = f2b(v);
        }
        *(us4*)&((unsigned short*)Cv)[g.coff + (long)col * ldc + row] = o;
      }
  } else {
#pragma unroll
    for (int m = 0; m < 4; ++m)
#pragma unroll
      for (int nn = 0; nn < 4; ++nn)
#pragma unroll
        for (int r = 0; r < 4; ++r) {
          float v = alpha * acc[m][nn][r] + bv[nn];
          if (ACT == 1) v = LEAKY(v);
          long off = g.coff + (long)s * sC2 +
                     (long)(m0 + wr + m * 16 + rrow + r) * ldc + n0 + wc +
                     nn * 16 + rl;
          if (CMODE == 1)
            ((unsigned short*)Cv)[off] = f2b(v);
          else
            ((float*)Cv)[off] = v;
        }
  }
}

// ---------------------------------------------------------------------------
// Fused BatchNorm on h^T (512 features x 16384 samples), bf16, in-place.
// ---------------------------------------------------------------------------
__global__ __launch_bounds__(256) void bn_fused(
    unsigned short* __restrict__ X,
    const float* __restrict__ g1, const float* __restrict__ be1,
    const float* __restrict__ g2, const float* __restrict__ be2) {
  const int f = blockIdx.x;
  const int z = blockIdx.z;
  unsigned short* p = X + (long)z * (8L << 20) + (long)f * 16384;
  const int tid = threadIdx.x;
  us4 v[16];
  float s = 0.f, q = 0.f;
#pragma unroll
  for (int k = 0; k < 16; ++k) {
    v[k] = *(const us4*)&p[(k * 256 + tid) * 4];
#pragma unroll
    for (int j = 0; j < 4; ++j) {
      const float x = b2f(v[k][j]);
      s += x; q += x * x;
    }
  }
#pragma unroll
  for (int mask = 1; mask < 64; mask <<= 1) {
    s += __shfl_xor(s, mask, 64);
    q += __shfl_xor(q, mask, 64);
  }
  __shared__ float rs[8];
  const int wv = tid >> 6;
  if ((tid & 63) == 0) { rs[wv] = s; rs[4 + wv] = q; }
  __syncthreads();
  s = rs[0] + rs[1] + rs[2] + rs[3];
  q = rs[4] + rs[5] + rs[6] + rs[7];
  const float mu = s * (1.f / 16384.f);
  const float var = q * (1.f / 16384.f) - mu * mu;
  const float gg = (z ? g2 : g1)[f];
  const float bb0 = (z ? be2 : be1)[f];
  const float rstd = rsqrtf(var + 1e-5f) * gg;
  const float bb = bb0 - mu * rstd;
#pragma unroll
  for (int k = 0; k < 16; ++k) {
    us4 o;
#pragma unroll
    for (int j = 0; j < 4; ++j) {
      const float y = b2f(v[k][j]) * rstd + bb;
      o[j] = f2b(LEAKY(y));
    }
    *(us4*)&p[(k * 256 + tid) * 4] = o;
  }
}

// ---------------------------------------------------------------------------
// bf16 MFMA flash attention, both attentions in one dispatch (z = 8).
// NO-MAX softmax (Q pre-scaled to log2 domain).
// R13: KVBLK=128 (2 tiles per barrier pair -> 16 barriers), Q fragments
// loaded straight from global (no Qs LDS; LDS = 40 KB -> 4 blocks/CU),
// l-reduction deferred to a single end-of-kernel shuffle pair.
// Ps is wave-private (rows w*16..w*16+15) -> no barrier needed around it.
// ---------------------------------------------------------------------------
__global__ __launch_bounds__(256) void attn_mfma(
    const unsigned short* __restrict__ Q, const unsigned short* __restrict__ K,
    const unsigned short* __restrict__ Vt, unsigned short* __restrict__ O) {
  const int qb = blockIdx.x, h = blockIdx.y;
  const int n = blockIdx.z & 3, sel = blockIdx.z >> 2;
  Q += (long)sel * 4194304;
  K += (long)sel * 4194304;
  Vt += (long)sel * 2097152;
  O += (long)sel * 2097152;
  const int tid = threadIdx.x;
  const int lane = tid & 63, w = tid >> 6;
  const int rl = lane & 15, lg = lane >> 4;
  __shared__ unsigned short Ks[8192];
  __shared__ unsigned short Vs[8192];
  __shared__ unsigned short Ps[4096];
  const int q = w * 16 + rl;
  // Q fragments straight from global: contiguous 16B per lane, read once.
  const unsigned short* Qrow =
      Q + ((long)n * 1024 + qb * 64 + q) * 512 + h * 64;
  const short8b qr0 = *(const short8b*)&Qrow[lg * 8];
  const short8b qr1 = *(const short8b*)&Qrow[32 + lg * 8];
  float l_r = 0.f;
  f32x4 po[4];
#pragma unroll
  for (int i = 0; i < 4; ++i) po[i] = (f32x4){0.f, 0.f, 0.f, 0.f};
  const unsigned short* Kg0 = K + ((long)n * 1024) * 512 + h * 64;
  const unsigned short* Vg0 = Vt + (long)n * 524288 + (long)(h * 64) * 1024;
  for (int kt = 0; kt < 8; ++kt) {
    __syncthreads();
    stage64(Kg0 + (long)(kt * 128) * 512, 512, Ks, lane, w);
    stage64(Kg0 + (long)(kt * 128 + 64) * 512, 512, Ks + 4096, lane, w);
    stage64(Vg0 + kt * 128, 1024, Vs, lane, w);
    stage64(Vg0 + kt * 128 + 64, 1024, Vs + 4096, lane, w);
    __syncthreads();
#pragma unroll
    for (int hf = 0; hf < 2; ++hf) {
      const unsigned short* Ksh = Ks + hf * 4096;
      const unsigned short* Vsh = Vs + hf * 4096;
      f32x4 sa[4];
#pragma unroll
      for (int i = 0; i < 4; ++i) sa[i] = (f32x4){0.f, 0.f, 0.f, 0.f};
#pragma unroll
      for (int kk = 0; kk < 2; ++kk) {
        const short8b qf = kk ? qr1 : qr0;
#pragma unroll
        for (int mt = 0; mt < 4; ++mt) {
          const short8b kf = ldsw(Ksh, mt * 16 + rl, 4 * kk + lg);
          sa[mt] =
              __builtin_amdgcn_mfma_f32_16x16x32_bf16(kf, qf, sa[mt], 0, 0, 0);
        }
      }
#pragma unroll
      for (int mt = 0; mt < 4; ++mt) {
        us4 o;
#pragma unroll
        for (int r = 0; r < 4; ++r) {
          const float p = exp2f(sa[mt][r]);
          l_r += p;
          o[r] = f2b(p);
        }
        const int c16 = (4 * mt + lg) >> 1;
        *(us4*)&Ps[q * 64 + ((c16 ^ (q & 7)) << 3) + ((lg & 1) << 2)] = o;
      }
#pragma unroll
      for (int kk = 0; kk < 2; ++kk) {
        const short8b pf = ldsw(Ps, q, 4 * kk + lg);
#pragma unroll
        for (int nt = 0; nt < 4; ++nt) {
          const short8b vf = ldsw(Vsh, nt * 16 + rl, 4 * kk + lg);
          po[nt] =
              __builtin_amdgcn_mfma_f32_16x16x32_bf16(pf, vf, po[nt], 0, 0, 0);
        }
      }
    }
  }
  // deferred l reduction (lanes with same rl hold disjoint key subsets)
  l_r += __shfl_xor(l_r, 16, 64);
  l_r += __shfl_xor(l_r, 32, 64);
  float invr[4];
#pragma unroll
  for (int r = 0; r < 4; ++r) invr[r] = 1.f / __shfl(l_r, lg * 4 + r, 64);
  const long ob = ((long)n * 1024 + qb * 64 + w * 16) * 512 + h * 64;
#pragma unroll
  for (int nt = 0; nt < 4; ++nt)
#pragma unroll
    for (int r = 0; r < 4; ++r)
      O[ob + (long)(lg * 4 + r) * 512 + nt * 16 + rl] = f2b(po[nt][r] * invr[r]);
}

// ---------------------------------------------------------------------------
// Softmax pass 1: per-row max & 1/sum, plus column sums of softmax(A).
// ---------------------------------------------------------------------------
__global__ __launch_bounds__(256) void softmax_cs(const float* __restrict__ D,
                                                  float* __restrict__ RS,
                                                  float* __restrict__ CS) {
  __shared__ float colacc[2048];
  __shared__ float red[8];
  const int tid = threadIdx.x;
  const int wv = tid >> 6, ln = tid & 63;
#pragma unroll
  for (int k = 0; k < 8; ++k) colacc[tid + k * 256] = 0.f;
  __syncthreads();
  const int r0 = blockIdx.x * 8;
  const int n = r0 >> 11;
  for (int rr = 0; rr < 8; ++rr) {
    const float* p = D + (long)(r0 + rr) * 2048;
    float v[8];
    float mx = -1e30f;
#pragma unroll
    for (int k = 0; k < 8; ++k) {
      v[k] = p[tid + k * 256];
      mx = fmaxf(mx, v[k]);
    }
#pragma unroll
    for (int mask = 1; mask < 64; mask <<= 1) mx = fmaxf(mx, __shfl_xor(mx, mask, 64));
    if (ln == 0) red[wv] = mx;
    __syncthreads();
    mx = fmaxf(fmaxf(red[0], red[1]), fmaxf(red[2], red[3]));
    float sum = 0.f;
#pragma unroll
    for (int k = 0; k < 8; ++k) {
      v[k] = __expf(v[k] - mx);
      sum += v[k];
    }
#pragma unroll
    for (int mask = 1; mask < 64; mask <<= 1) sum += __shfl_xor(sum, mask, 64);
    if (ln == 0) red[4 + wv] = sum;
    __syncthreads();
    sum = red[4] + red[5] + red[6] + red[7];
    const float inv = 1.f / sum;
    if (tid == 0) {
      RS[(r0 + rr) * 2] = mx;
      RS[(r0 + rr) * 2 + 1] = inv;
    }
#pragma unroll
    for (int k = 0; k < 8; ++k) colacc[tid + k * 256] += v[k] * inv;
    __syncthreads();
  }
#pragma unroll
  for (int k = 0; k < 8; ++k)
    atomicAdd(&CS[n * 2048 + tid + k * 256], colacc[tid + k * 256]);
}

// Pass 2: recompute softmax, apply column normalize. Grid-stride (2048 x 8).
__global__ __launch_bounds__(256) void final_scale(float* __restrict__ D,
                                                   const float* __restrict__ RS,
                                                   const float* __restrict__ CS) {
#pragma unroll
  for (int it = 0; it < 8; ++it) {
    const long i = ((long)(blockIdx.x + it * 2048) * 256 + threadIdx.x) * 4;
    const long row = i >> 11;
    const int n = (int)(row >> 11);
    const int j = (int)(i & 2047);
    const float mx = RS[row * 2];
    const float inv = RS[row * 2 + 1];
    float4 v = *(float4*)&D[i];
    const float* c = &CS[n * 2048 + j];
    v.x = __expf(v.x - mx) * inv * (c[0] > 0.f ? 1.f / c[0] : 0.f);
    v.y = __expf(v.y - mx) * inv * (c[1] > 0.f ? 1.f / c[1] : 0.f);
    v.z = __expf(v.z - mx) * inv * (c[2] > 0.f ? 1.f / c[2] : 0.f);
    v.w = __expf(v.w - mx) * inv * (c[3] > 0.f ? 1.f / c[3] : 0.f);
    *(float4*)&D[i] = v;
  }
}

// ---------------------------------------------------------------------------
extern "C" void kernel_launch(void* const* d_in, const int* in_sizes, int n_in,
                              void* d_out, int out_size, void* d_ws,
                              size_t ws_size, hipStream_t stream) {
  const float* x1 = (const float*)d_in[0];
  const float* x2 = (const float*)d_in[1];
  const float* enc1 = (const float*)d_in[2];
  const float* enc2 = (const float*)d_in[3];
  const float* mlp_b1 = (const float*)d_in[5];
  const float* mlp_b2 = (const float*)d_in[7];
  const float* mlp_g = (const float*)d_in[8];
  const float* mlp_be = (const float*)d_in[9];
  const float* nlp_b1 = (const float*)d_in[11];
  const float* nlp_b2 = (const float*)d_in[13];
  const float* nlp_g = (const float*)d_in[14];
  const float* nlp_be = (const float*)d_in[15];
  float* out = (float*)d_out;

  unsigned short* W = (unsigned short*)d_ws;
  const long M1 = 1L << 20;
  const long S = 262144;
  const float K2 = 0.18033688f;  // 0.125 * log2(e)
  // Rolling layout (us units), lifetimes disjoint-in-time:
  //  0.. 2M : Pt                               [dead after node_enc]
  //  4..12M : ENC -> E1/E2 (4..8M) -> A1P/A2P (8..12M)
  // 12..16M : E1T                              [dead after edge decode]
  // 16..19M : WT                               [dead after fc]
  // 20..36M : NE -> H1T/H2T                    [dead after edge decode]
  // 36..52M : MID (lin1) -> edge bf16 partials (16M us)
  //           -> QKQK (36..44M), V^T (44..48M), AO (48..52M)
  unsigned short* Pt = W;
  unsigned short* ENC = W + 4 * M1;
  unsigned short* E1T = W + 12 * M1;
  unsigned short* WT = W + 16 * M1;
  unsigned short* NE = W + 20 * M1;
  unsigned short* H1T = W + 20 * M1;
  unsigned short* MID = W + 36 * M1;
  unsigned short* PB = W + 36 * M1;   // edge bf16 split-K partials (16M us)
  unsigned short* E1 = W + 4 * M1;
  unsigned short* E2 = W + 6 * M1;
  unsigned short* QKV = W + 36 * M1;
  unsigned short* VT = W + 44 * M1;
  unsigned short* AO = W + 48 * M1;
  unsigned short* A1P = W + 8 * M1;
  unsigned short* A2P = W + 10 * M1;
  float* ST = (float*)(W + 56 * M1);
  float* CS = ST + 2048;
  float* RS = CS + 8192;

  const dim3 T(256);
  const long sP = 262144;
  const long sNE = 2097152;
  const long sE = 524288;
  const long sD = 4194304;

  // --- CS memset early (region dead until softmax) ---
  hipMemsetAsync(CS, 0, 8192 * sizeof(float), stream);

  // --- prologue: separate specialized kernels ---
  prep_pool_t<<<dim3(64, 4, 8), T, 0, stream>>>(x1, x2, Pt);
  convert2_f2b<<<2048, T, 0, stream>>>(enc1, enc2, ENC);
  transpose_f2b<<<dim3(16, 64), T, 0, stream>>>(enc1, E1T, 4096, 1024);
  WPtrs wp;
  wp.p[0] = (const float*)d_in[4];   wp.sc[0] = 1.f;   // mlp_w1
  wp.p[1] = (const float*)d_in[6];   wp.sc[1] = 1.f;   // mlp_w2
  wp.p[2] = (const float*)d_in[10];  wp.sc[2] = 1.f;   // nlp_w1
  wp.p[3] = (const float*)d_in[12];  wp.sc[3] = 1.f;   // nlp_w2
  wp.p[4] = (const float*)d_in[16];  wp.sc[4] = K2;    // a1_wq (log2-scaled)
  wp.p[5] = (const float*)d_in[18];  wp.sc[5] = 1.f;   // a1_wk
  wp.p[6] = (const float*)d_in[24];  wp.sc[6] = K2;    // a2_wq (log2-scaled)
  wp.p[7] = (const float*)d_in[26];  wp.sc[7] = 1.f;   // a2_wk
  wp.p[8] = (const float*)d_in[20];  wp.sc[8] = 1.f;   // a1_wv
  wp.p[9] = (const float*)d_in[28];  wp.sc[9] = 1.f;   // a2_wv
  wp.p[10] = (const float*)d_in[22]; wp.sc[10] = 1.f;  // a1_fc
  wp.p[11] = (const float*)d_in[30]; wp.sc[11] = 1.f;  // a2_fc
  wtrans<<<dim3(8, 8, 12), T, 0, stream>>>(wp, WT);

  // --- node_enc for BOTH branches: z=16 (inp x pr x n) -> NE ---
  {
    GDescs g{};
    for (int inp = 0; inp < 2; ++inp)
      for (int pr = 0; pr < 2; ++pr)
        for (int nn = 0; nn < 4; ++nn)
          g.d[inp * 8 + pr * 4 + nn] = {
              ENC + (long)pr * (4 * M1), Pt + (long)inp * M1 + nn * sP,
              (long)inp * (8 * M1) + (long)nn * sNE + pr * 256, nullptr, 0, 1.f};
    gemm_z<0, 1, 1><<<dim3(2, 32, 16), T, 0, stream>>>(g, NE, 1024, 1024,
                                                       1024, 512, 0, 1.f);
  }
  // --- lin1 both branches (z=2) -> MID ---
  {
    GDescs g{};
    g.d[0] = {NE, WT + 0 * S, 0, mlp_b1, 0, 1.f};
    g.d[1] = {NE + 8 * M1, WT + 2 * S, 8 * M1, nlp_b1, 0, 1.f};
    gemm_z<1, 1, 1><<<dim3(4, 128, 2), T, 0, stream>>>(g, MID, 512, 512, 512,
                                                       512, 0, 1.f);
  }
  // --- lin2^T both branches (z=2) -> H1T/H2T (over NE, dead) ---
  {
    GDescs g{};
    g.d[0] = {MID, WT + 1 * S, 0, mlp_b2, 0, 1.f};
    g.d[1] = {MID + 8 * M1, WT + 3 * S, 8 * M1, nlp_b2, 0, 1.f};
    gemm_z<0, 3, 1><<<dim3(4, 128, 2), T, 0, stream>>>(g, H1T, 512, 512, 512,
                                                       16384, 0, 1.f);
  }
  bn_fused<<<dim3(512, 1, 2), T, 0, stream>>>(H1T, mlp_g, mlp_be, nlp_g, nlp_be);

  // --- edge decode: z = 8 descs x split-K 4, bf16 partials in MID region ---
  {
    GDescs g{};
    for (int d = 0; d < 8; ++d)
      g.d[d] = {E1T, H1T + (long)(d >> 2) * (8 * M1) + (d & 3) * 4096,
                (long)d * 524288, nullptr, 0, 1.f};
    gemm_z<0, 1, 4><<<dim3(4, 8, 32), T, 0, stream>>>(g, PB, 1024, 4096,
                                                      16384, 512, 4194304,
                                                      1.f / 1024.f);
  }
  addcvt4<<<1024, T, 0, stream>>>(PB, E1);

  // --- projections: Q1,K1,Q2,K2,V1,V2 in ONE dispatch (z=6, per-desc mode) ---
  {
    GDescs g{};
    g.d[0] = {E2, WT + 4 * S, 0, (const float*)d_in[17], 1, K2};
    g.d[1] = {E1, WT + 5 * S, 2 * M1, (const float*)d_in[19], 1, 1.f};
    g.d[2] = {E1, WT + 6 * S, 4 * M1, (const float*)d_in[25], 1, K2};
    g.d[3] = {E2, WT + 7 * S, 6 * M1, (const float*)d_in[27], 1, 1.f};
    g.d[4] = {E1, WT + 8 * S, 8 * M1, (const float*)d_in[21], 2, 1.f};
    g.d[5] = {E2, WT + 9 * S, 10 * M1, (const float*)d_in[29], 2, 1.f};
    gemm_z<0, 4, 1><<<dim3(4, 32, 6), T, 0, stream>>>(g, QKV, 512, 512, 512,
                                                      512, 0, 1.f);
  }

  // --- both attentions ---
  attn_mfma<<<dim3(16, 8, 8), T, 0, stream>>>(QKV, QKV + 2 * M1, VT, AO);

  // --- fc for both attentions -> A1P/A2P ---
  {
    GDescs g{};
    g.d[0] = {AO, WT + 10 * S, 0, (const float*)d_in[23], 0, 1.f};
    g.d[1] = {AO + 2 * M1, WT + 11 * S, 2 * M1, (const float*)d_in[31], 0, 1.f};
    gemm_z<0, 1, 1><<<dim3(4, 32, 2), T, 0, stream>>>(g, A1P, 512, 512, 512,
                                                      512, 0, 1.f);
  }

  // --- logits: all 4 quadrants x 4 n in one dispatch (z=16) ---
  {
    GDescs g{};
    for (int q = 0; q < 4; ++q)
      for (int n = 0; n < 4; ++n) {
        const unsigned short* A = (q < 2 ? A1P : A2P) + n * sE;
        const unsigned short* B = ((q == 0 || q == 2) ? A2P : A1P) + n * sE;
        const long coff =
            (long)n * sD + (q & 1) * 1024 + (long)(q >> 1) * 2097152;
        g.d[q * 4 + n] = {A, B, coff, nullptr, 0, 1.f};
      }
    gemm_z<0, 0, 1><<<dim3(8, 8, 16), T, 0, stream>>>(g, out, 512, 512, 512,
                                                      2048, 0, 1.f);
  }

  // --- softmax + column normalization (2 passes, no middle write) ---
  softmax_cs<<<1024, T, 0, stream>>>(out, RS, CS);
  final_scale<<<2048, T, 0, stream>>>(out, RS, CS);
}